// Round 11
// baseline (487.495 us; speedup 1.0000x reference)
//
#include <hip/hip_runtime.h>
#include <math.h>

// GCN(2 layers, N=32768, E=524288, d=128) -> 2-layer cross-attention
// transformer (B=32, M=1024, d=128, H=8, dh=16, dff=512).
// R20: fp8-e4m3 gather table. Gather was memory-system-bound (R19's scalar-
//   index rewrite was neutral): hsh = 8MB bf16 > 4MB per-XCD L2, random rows
//   -> ~50% L2 hit. Now GCN gemm (mode 3) writes h as fp8 e4m3 scaled x16
//   (values ~0.9, mid-normal; x1/16 folded into gather's dinv): table = 4MB
//   = L2-resident, bytes/row halved (128B, ushort/lane coalesced). Convert
//   via gfx950 HW cvt_pk (1 VALU per pair, replaces bflo/bfhi). Numerics:
//   fp8 RNE ~2% rel on pre-aggregation h, aggregated over ~17 random-sign
//   neighbors + 2x LN downstream -> predicted absmax <= 0.06 (thr 0.095).
// R19 recap (481.8us): swapped-QK attn (52.2us floor), gemm64 R17-form
//   8wg/CU, gemm_ln 32x128 4wg/CU, scalar-index gather, prep/qkv fused,
//   bufY 256B-aligned, atomics at workspace bottom.

typedef __attribute__((ext_vector_type(8)))  short short8;   // 8 bf16 = 4 VGPRs
typedef __attribute__((ext_vector_type(2)))  float f32x2;
typedef __attribute__((ext_vector_type(4)))  float f32x4;
typedef __attribute__((ext_vector_type(16))) float f32x16;

__device__ __forceinline__ unsigned short f2bf(float x) {   // RNE fp32->bf16
    unsigned u = __builtin_bit_cast(unsigned, x);
    u = (u + 0x7FFFu + ((u >> 16) & 1u)) >> 16;
    return (unsigned short)u;
}
__device__ __forceinline__ float bflo(unsigned u) { return __builtin_bit_cast(float, u << 16); }
__device__ __forceinline__ float bfhi(unsigned u) { return __builtin_bit_cast(float, u & 0xffff0000u); }
__device__ __forceinline__ float fast_exp2(float x) {       // D = 2^S0
    float r; asm("v_exp_f32 %0, %1" : "=v"(r) : "v"(x)); return r;
}
__device__ __forceinline__ unsigned char f2fp8(float x) {   // f32 -> OCP e4m3
    int pk = __builtin_amdgcn_cvt_pk_fp8_f32(x, x, 0, false);
    return (unsigned char)(pk & 0xff);
}

// ---------------------------------------------------------------------------
// CSR build
// ---------------------------------------------------------------------------
__global__ void count_kernel(const int* __restrict__ dst, int* __restrict__ cnt, int E) {
    int e = blockIdx.x * 256 + threadIdx.x;
    if (e < E) atomicAdd(&cnt[dst[e]], 1);
}

// partial[b] = sum of cnt[b*256 .. b*256+255]
__global__ __launch_bounds__(256)
void scanA_kernel(const int* __restrict__ cnt, int* __restrict__ partial)
{
    __shared__ int wsum[4];
    int t = threadIdx.x;
    int v = cnt[blockIdx.x * 256 + t];
    #pragma unroll
    for (int off = 32; off; off >>= 1) v += __shfl_xor(v, off, 64);
    if ((t & 63) == 0) wsum[t >> 6] = v;
    __syncthreads();
    if (t == 0) partial[blockIdx.x] = wsum[0] + wsum[1] + wsum[2] + wsum[3];
}

// base = exclusive scan of partial[0..127]
__global__ __launch_bounds__(128)
void scanB_kernel(const int* __restrict__ partial, int* __restrict__ base)
{
    __shared__ int p[128];
    int t = threadIdx.x;
    int v = partial[t];
    p[t] = v;
    __syncthreads();
    for (int o = 1; o < 128; o <<= 1) {
        int q = (t >= o) ? p[t - o] : 0;
        __syncthreads();
        p[t] += q;
        __syncthreads();
    }
    base[t] = p[t] - v;   // exclusive
}

// off[i] = base[b] + exclusive-scan-within-block; cursor = off; dinv = rsqrt
__global__ __launch_bounds__(256)
void scanC_kernel(const int* __restrict__ cnt, const int* __restrict__ base,
                  int* __restrict__ off, int* __restrict__ cursor,
                  float* __restrict__ dinv, int N, int E)
{
    __shared__ int p[256];
    int t = threadIdx.x, b = blockIdx.x;
    int i = b * 256 + t;
    int c = cnt[i];
    p[t] = c;
    __syncthreads();
    for (int o = 1; o < 256; o <<= 1) {
        int q = (t >= o) ? p[t - o] : 0;
        __syncthreads();
        p[t] += q;
        __syncthreads();
    }
    int ex = base[b] + p[t] - c;
    off[i] = ex;
    cursor[i] = ex;
    dinv[i] = rsqrtf((float)c + 1.0f);
    if (b == 0 && t == 0) off[N] = E;
}

__global__ void place_kernel(const int* __restrict__ src, const int* __restrict__ dst,
                             int* __restrict__ cursor, int* __restrict__ csr_src, int E)
{
    int e = blockIdx.x * 256 + threadIdx.x;
    if (e < E) {
        int p = atomicAdd(&cursor[dst[e]], 1);
        csr_src[p] = src[e];
    }
}

// ---------------------------------------------------------------------------
// prep_kernel: fused conv(xraw->xrawh) | copyconv(enc->bufY,bufYh) | wtrans.
// Grid 1D: [0,nconv) conv, [nconv,2*nconv) copyconv, rest 256-block slots.
// Wq scale = 0.25 * log2(e): scores come out pre-multiplied for exp2.
// ---------------------------------------------------------------------------
__global__ __launch_bounds__(256)
void prep_kernel(const float* __restrict__ xraw, unsigned short* __restrict__ xrawh,
                 const float* __restrict__ enc, float* __restrict__ bufY,
                 unsigned short* __restrict__ bufYh,
                 const float* Wg1, const float* Wg2, const float* Wq, const float* Wk,
                 const float* Wv, const float* Wo, const float* Wff1, const float* Wff2,
                 unsigned short* __restrict__ out, int nconv)
{
    const int bid = blockIdx.x, tid = threadIdx.x;
    if (bid < nconv) {                       // conv: xraw -> xrawh (bf16)
        int i = bid * 256 + tid;
        float4 v = ((const float4*)xraw)[i];
        ushort4 h; h.x = f2bf(v.x); h.y = f2bf(v.y); h.z = f2bf(v.z); h.w = f2bf(v.w);
        ((ushort4*)xrawh)[i] = h;
        return;
    }
    if (bid < 2 * nconv) {                   // copyconv: enc -> bufY (f32) + bufYh
        int i = (bid - nconv) * 256 + tid;
        float4 v = ((const float4*)enc)[i];
        ((float4*)bufY)[i] = v;
        ushort4 h; h.x = f2bf(v.x); h.y = f2bf(v.y); h.z = f2bf(v.z); h.w = f2bf(v.w);
        ((ushort4*)bufYh)[i] = h;
        return;
    }
    const int bid2 = bid - 2 * nconv;
    const int slot = bid2 >> 8;              // 14 slots x 256 blocks
    const int bx   = bid2 & 255;
    const float* src; int ks; int Ns; size_t doff; float scale = 1.0f;
    if      (slot == 0)  { src = Wg1;                        ks = 7; Ns = 128; doff = 0; }
    else if (slot == 1)  { src = Wg2;                        ks = 7; Ns = 128; doff = 16384; }
    else if (slot <= 3)  { src = Wq  + (slot - 2)  * 16384;  ks = 7; Ns = 128; doff = 32768  + (size_t)(slot - 2)  * 16384; scale = 0.36067376022f; }
    else if (slot <= 5)  { src = Wk  + (slot - 4)  * 16384;  ks = 7; Ns = 128; doff = 65536  + (size_t)(slot - 4)  * 32768; }
    else if (slot <= 7)  { src = Wv  + (slot - 6)  * 16384;  ks = 7; Ns = 128; doff = 65536  + (size_t)(slot - 6)  * 32768 + 16384; }
    else if (slot <= 9)  { src = Wo  + (slot - 8)  * 16384;  ks = 7; Ns = 128; doff = 131072 + (size_t)(slot - 8)  * 16384; }
    else if (slot <= 11) { src = Wff1 + (slot - 10) * 65536; ks = 7; Ns = 512; doff = 163840 + (size_t)(slot - 10) * 65536; }
    else                 { src = Wff2 + (slot - 12) * 65536; ks = 9; Ns = 128; doff = 294912 + (size_t)(slot - 12) * 65536; }
    const int total = Ns << ks;
    int id = bx * 256 + tid;
    if (id >= total) return;
    int n = id >> ks;
    int k = id & ((1 << ks) - 1);
    out[doff + id] = f2bf(src[(size_t)k * Ns + n] * scale);
}

// ---------------------------------------------------------------------------
// gemm64_body: 64x64 tile, BK=64, 18.4 KB LDS -> 8 wg/CU (R17 form).
// Wave = one 32x32 MFMA tile. mode 1: bf16 out (+bias/relu/rowscale), ldc.
// mode 2: KV split (col<128 -> K natural; col>=128 -> V transposed [b,h,d,slot]
//         with slot mapping: key w=32t+16b+4qd+c -> slot=32t+8qd+4b+c).
// mode 3 (R20): fp8-e4m3 out x16 (GCN h table; ldc fixed 128, byte stores).
// C/D: col=lane&31, row=(reg&3)+8*(reg>>2)+4*(lane>>5)  [verified mapping].
// ---------------------------------------------------------------------------
__device__ __forceinline__
void gemm64_body(unsigned short* As, unsigned short* Ws,
                 const unsigned short* __restrict__ A,
                 const unsigned short* __restrict__ Wt,
                 void* __restrict__ C, void* __restrict__ C2, int K, int ldc,
                 const float* __restrict__ bias, const float* __restrict__ rowscale,
                 int relu, int mode, int bx, int by)
{
    const int tid  = threadIdx.x;
    const int lane = tid & 63, wave = tid >> 6;
    const int m31 = lane & 31, hi = lane >> 5;
    const int row0 = bx * 64;
    const int c0   = by * 64;
    const int wrow = (wave & 1) * 32;
    const int wcol = (wave >> 1) * 32;
    const int sr = tid >> 2, sk = (tid & 3) * 16;

    f32x16 acc = {};

    for (int kt = 0; kt < K; kt += 64) {
        if (kt) __syncthreads();
        *(short8*)&As[sr * 72 + sk]     = *(const short8*)&A [(size_t)(row0 + sr) * K + kt + sk];
        *(short8*)&As[sr * 72 + sk + 8] = *(const short8*)&A [(size_t)(row0 + sr) * K + kt + sk + 8];
        *(short8*)&Ws[sr * 72 + sk]     = *(const short8*)&Wt[(size_t)(c0   + sr) * K + kt + sk];
        *(short8*)&Ws[sr * 72 + sk + 8] = *(const short8*)&Wt[(size_t)(c0   + sr) * K + kt + sk + 8];
        __syncthreads();
        #pragma unroll
        for (int ks = 0; ks < 4; ++ks) {
            short8 af = *(const short8*)&As[(wrow + m31) * 72 + ks * 16 + hi * 8];
            short8 bf = *(const short8*)&Ws[(wcol + m31) * 72 + ks * 16 + hi * 8];
            acc = __builtin_amdgcn_mfma_f32_32x32x16_bf16(af, bf, acc, 0, 0, 0);
        }
    }

    const int col = c0 + wcol + m31;
    #pragma unroll
    for (int r = 0; r < 16; ++r) {
        const int row = row0 + wrow + (r & 3) + 8 * (r >> 2) + 4 * hi;
        float v = acc[r];
        if (rowscale) v *= rowscale[row];
        if (bias) v += bias[col];
        if (relu) v = fmaxf(v, 0.0f);
        if (mode == 1) {
            ((unsigned short*)C)[(size_t)row * ldc + col] = f2bf(v);
        } else if (mode == 3) {   // fp8 h-table, x16 scale (consumer folds /16)
            ((unsigned char*)C)[(size_t)row * 128 + col] = f2fp8(v * 16.0f);
        } else {    // KV: K natural (128 cols), V transposed [b,h,d,slot]
            if (col < 128) {
                ((unsigned short*)C)[(size_t)row * 128 + col] = f2bf(v);
            } else {
                int ch = col - 128, hh = ch >> 4, dd = ch & 15;
                int kg = row & 1023;                       // global key in batch
                int w  = kg & 127;                         // within 128-chunk
                // slot: w = 32t+16b+4qd+c -> slot = 32t+8qd+4b+c
                int slot = ((w >> 5) << 5) | (((w >> 2) & 3) << 3)
                         | (((w >> 4) & 1) << 2) | (w & 3);
                int kpos = (kg & ~127) | slot;
                ((unsigned short*)C2)[(((size_t)(row >> 10) * 8 + hh) * 16 + dd) * 1024
                                      + kpos] = f2bf(v);
            }
        }
    }
}

__global__ __launch_bounds__(256)
void gemm64_kernel(const unsigned short* __restrict__ A,
                   const unsigned short* __restrict__ Wt,
                   void* __restrict__ C, void* __restrict__ C2, int K,
                   const float* __restrict__ bias, const float* __restrict__ rowscale,
                   int relu, int mode)
{
    __shared__ unsigned short As[64 * 72];
    __shared__ unsigned short Ws[64 * 72];
    gemm64_body(As, Ws, A, Wt, C, C2, K, gridDim.y * 64, bias, rowscale, relu, mode,
                blockIdx.x, blockIdx.y);
}

// Q-proj (y<2) + KV-proj (y in 2..5) in one dispatch. Branch is block-uniform.
__global__ __launch_bounds__(256)
void qkv_kernel(const unsigned short* __restrict__ Yh, const unsigned short* __restrict__ wtq,
                unsigned short* __restrict__ Qh,
                const unsigned short* __restrict__ Bh, const unsigned short* __restrict__ wtkv,
                unsigned short* __restrict__ Kg, unsigned short* __restrict__ Vtg)
{
    __shared__ unsigned short As[64 * 72];
    __shared__ unsigned short Ws[64 * 72];
    if (blockIdx.y < 2)
        gemm64_body(As, Ws, Yh, wtq, Qh, nullptr, 128, 128, nullptr, nullptr, 0, 1,
                    blockIdx.x, blockIdx.y);
    else
        gemm64_body(As, Ws, Bh, wtkv, Kg, Vtg, 128, 256, nullptr, nullptr, 0, 2,
                    blockIdx.x, blockIdx.y - 2);
}

// ---------------------------------------------------------------------------
// gemm_ln: 32x128 tile, BK=64; per-wave 32x32 (one f32x16 acc).
// Grid BM/32 = 1024 blocks; LDS 23.0 KB -> 4 blocks/CU.
// Epilogue = bias + residual + LayerNorm; writes resid_out f32 + yh bf16.
// LDS reused as f32 stash [32][130]. LN row = 8 threads x 16 cols.
// ---------------------------------------------------------------------------
__global__ __launch_bounds__(256)
void gemm_ln_kernel(const unsigned short* __restrict__ A,
                    const unsigned short* __restrict__ Wt, int K,
                    const float* __restrict__ bias,
                    const float* __restrict__ resid_in, float* __restrict__ resid_out,
                    unsigned short* __restrict__ yh,
                    const float* __restrict__ lng, const float* __restrict__ lnb)
{
    __shared__ __align__(16) unsigned char smraw[23040];  // As[32][72] 4608 | Ws[128][72] 18432
    unsigned short* As = (unsigned short*)smraw;           // [32][72]
    unsigned short* Ws = (unsigned short*)(smraw + 4608);  // [128][72]

    const int tid  = threadIdx.x;
    const int lane = tid & 63, wave = tid >> 6;
    const int m31 = lane & 31, hi = lane >> 5;
    const int row0 = blockIdx.x * 32;
    const int wcol = wave * 32;                     // wave owns cols wcol..wcol+31
    const int sr = tid >> 3, sk = (tid & 7) * 8;    // A staging: 32 rows x 8 slots
    const int wr = tid >> 1, wo = (tid & 1) * 32;   // W staging: 128 rows x 2 halves

    f32x16 acc = {};

    for (int kt = 0; kt < K; kt += 64) {
        if (kt) __syncthreads();
        *(short8*)&As[sr * 72 + sk]      = *(const short8*)&A [(size_t)(row0 + sr) * K + kt + sk];
        *(short8*)&Ws[wr * 72 + wo]      = *(const short8*)&Wt[(size_t)wr * K + kt + wo];
        *(short8*)&Ws[wr * 72 + wo + 8]  = *(const short8*)&Wt[(size_t)wr * K + kt + wo + 8];
        *(short8*)&Ws[wr * 72 + wo + 16] = *(const short8*)&Wt[(size_t)wr * K + kt + wo + 16];
        *(short8*)&Ws[wr * 72 + wo + 24] = *(const short8*)&Wt[(size_t)wr * K + kt + wo + 24];
        __syncthreads();
        #pragma unroll
        for (int ks = 0; ks < 4; ++ks) {
            short8 af = *(const short8*)&As[m31 * 72 + ks * 16 + hi * 8];
            short8 bf = *(const short8*)&Ws[(wcol + m31) * 72 + ks * 16 + hi * 8];
            acc = __builtin_amdgcn_mfma_f32_32x32x16_bf16(af, bf, acc, 0, 0, 0);
        }
    }

    // --- stash t into LDS, then per-row residual + LN ---
    __syncthreads();
    float* Ts = (float*)smraw;    // [32][130]
    {
        const int col = wcol + m31;
        #pragma unroll
        for (int r = 0; r < 16; ++r) {
            const int rl = (r & 3) + 8 * (r >> 2) + 4 * hi;
            float v = acc[r];
            if (bias) v += bias[col];
            Ts[rl * 130 + col] = v;
        }
    }
    __syncthreads();
    const int r  = tid >> 3;       // 0..31
    const int cq = tid & 7;        // 8 threads per row, 16 cols each
    const int row = row0 + r;
    float v[16], s1 = 0.f, s2 = 0.f;
    const float* yr = resid_in + (size_t)row * 128 + cq * 16;
    #pragma unroll
    for (int i = 0; i < 4; ++i) {
        float4 yv = *(const float4*)&yr[i * 4];
        float ys[4] = {yv.x, yv.y, yv.z, yv.w};
        #pragma unroll
        for (int j = 0; j < 4; ++j) {
            float t = Ts[r * 130 + cq * 16 + i * 4 + j] + ys[j];
            v[i * 4 + j] = t; s1 += t; s2 += t * t;
        }
    }
    s1 += __shfl_xor(s1, 1, 64); s1 += __shfl_xor(s1, 2, 64); s1 += __shfl_xor(s1, 4, 64);
    s2 += __shfl_xor(s2, 1, 64); s2 += __shfl_xor(s2, 2, 64); s2 += __shfl_xor(s2, 4, 64);
    const float mu  = s1 * (1.0f / 128.0f);
    const float inv = rsqrtf(s2 * (1.0f / 128.0f) - mu * mu + 1e-5f);
    float* outr = resid_out + (size_t)row * 128 + cq * 16;
    unsigned short* yhr = yh + (size_t)row * 128 + cq * 16;
    #pragma unroll
    for (int i = 0; i < 4; ++i) {
        float o0 = (v[i*4+0] - mu) * inv * lng[cq*16 + i*4 + 0] + lnb[cq*16 + i*4 + 0];
        float o1 = (v[i*4+1] - mu) * inv * lng[cq*16 + i*4 + 1] + lnb[cq*16 + i*4 + 1];
        float o2 = (v[i*4+2] - mu) * inv * lng[cq*16 + i*4 + 2] + lnb[cq*16 + i*4 + 2];
        float o3 = (v[i*4+3] - mu) * inv * lng[cq*16 + i*4 + 3] + lnb[cq*16 + i*4 + 3];
        float4 ov; ov.x = o0; ov.y = o1; ov.z = o2; ov.w = o3;
        *(float4*)&outr[i * 4] = ov;
        ushort4 hv; hv.x = f2bf(o0); hv.y = f2bf(o1); hv.z = f2bf(o2); hv.w = f2bf(o3);
        *(ushort4*)&yhr[i * 4] = hv;
    }
}

// ---------------------------------------------------------------------------
// GCN gather: fp8-e4m3 input rows (128 B, L2-resident 4MB table), bf16 out.
// One wave per node, 2 channels per lane (ushort = 2 fp8). Scalar neighbor
// indices (R19). Producer stored h x16 -> fold 1/16 into di.
// ---------------------------------------------------------------------------
__global__ __launch_bounds__(256)
void gather_kernel(const unsigned char* __restrict__ hs8, const int* __restrict__ csr_off,
                   const int* __restrict__ csr_src, const float* __restrict__ dinv,
                   const float* __restrict__ bias, unsigned short* __restrict__ out, int N)
{
    const int node = blockIdx.x * 4 + (threadIdx.x >> 6);
    const int lane = threadIdx.x & 63;
    const int s0 = __builtin_amdgcn_readfirstlane(csr_off[node]);
    const int s1 = __builtin_amdgcn_readfirstlane(csr_off[node + 1]);
    const unsigned short* hsu = (const unsigned short*)hs8;  // 2 fp8 per ushort

    unsigned short u = hsu[(size_t)node * 64 + lane];
    f32x2 f = __builtin_amdgcn_cvt_pk_f32_fp8((int)u, false);
    float a0 = f.x, a1 = f.y;

    int j = s0;
    for (; j + 4 <= s1; j += 4) {
        int i0 = csr_src[j];        // wave-uniform -> scalar pipe
        int i1 = csr_src[j + 1];
        int i2 = csr_src[j + 2];
        int i3 = csr_src[j + 3];
        unsigned short uA = hsu[(size_t)i0 * 64 + lane];
        unsigned short uB = hsu[(size_t)i1 * 64 + lane];
        unsigned short uC = hsu[(size_t)i2 * 64 + lane];
        unsigned short uD = hsu[(size_t)i3 * 64 + lane];
        f32x2 fA = __builtin_amdgcn_cvt_pk_f32_fp8((int)uA, false);
        f32x2 fB = __builtin_amdgcn_cvt_pk_f32_fp8((int)uB, false);
        f32x2 fC = __builtin_amdgcn_cvt_pk_f32_fp8((int)uC, false);
        f32x2 fD = __builtin_amdgcn_cvt_pk_f32_fp8((int)uD, false);
        a0 += (fA.x + fB.x) + (fC.x + fD.x);
        a1 += (fA.y + fB.y) + (fC.y + fD.y);
    }
    for (; j < s1; ++j) {
        int ib = csr_src[j];
        unsigned short ub = hsu[(size_t)ib * 64 + lane];
        f32x2 fb = __builtin_amdgcn_cvt_pk_f32_fp8((int)ub, false);
        a0 += fb.x; a1 += fb.y;
    }
    float di = dinv[node] * 0.0625f;   // undo producer's x16
    float v0 = fmaxf(a0 * di + bias[lane * 2],     0.0f);
    float v1 = fmaxf(a1 * di + bias[lane * 2 + 1], 0.0f);
    ((unsigned*)out)[(size_t)node * 64 + lane] =
        ((unsigned)f2bf(v1) << 16) | (unsigned)f2bf(v0);
}

// ---------------------------------------------------------------------------
// MFMA flash cross-attention. Block = (64q, head, batch), wave owns 16 q,
// 128-key chunks. Ks natural [128 keys][16 dims] (4KB), byte-linear staging.
// SWAPPED QK^T: s[g] = mfma(kb, qa) -> lane (quad,l16) holds scores for
// q=l16, keys {16g+4quad+r}. exp + pack feed PV's A-fragment directly
// (P[q=l16][slot quad*8+j], slot->key = 32t+16(j>>2)+4quad+(j&3)); Vtg is
// pre-permuted to this slot order by the KV GEMM. No P LDS. quad>=2 lanes:
// qa=0 (B zero) x kb-garbage (finite) = 0 for k=16..31. l = P*ones via MFMA.
// ---------------------------------------------------------------------------
__global__ __launch_bounds__(256)
void attn_mfma_kernel(const unsigned short* __restrict__ Qh,
                      const unsigned short* __restrict__ Kg,
                      const unsigned short* __restrict__ Vtg,
                      unsigned short* __restrict__ Obh)
{
    __shared__ __align__(16) unsigned short Ks[128 * 16];  // [key][dim 0..15]
    __shared__ __align__(16) unsigned short Vt[16 * 136];  // [dim][slot 0..127]

    const int tid  = threadIdx.x;
    const int lane = tid & 63, wave = tid >> 6;
    const int quad = lane >> 4, l16 = lane & 15;
    const int q0 = blockIdx.x * 64, h = blockIdx.y, b = blockIdx.z;

    // staging coords (fixed per thread)
    const int key  = tid >> 1, half = (tid & 1) * 8;
    const int dim  = tid >> 4, kc = (tid & 15) * 8;
    const unsigned short* Kp = &Kg[((size_t)b * 1024 + key) * 128 + h * 16 + half];
    const unsigned short* Vp = &Vtg[(((size_t)b * 8 + h) * 16 + dim) * 1024 + kc];

    short8 qa = {};
    if (quad < 2) {
        qa = *(const short8*)&Qh[((size_t)b * 1024 + q0 + wave * 16 + l16) * 128 + h * 16 + quad * 8];
    }

    const short one_bf = (short)0x3F80;       // bf16 1.0
    const short8 onesv = {one_bf, one_bf, one_bf, one_bf,
                          one_bf, one_bf, one_bf, one_bf};

    f32x4 o    = {0.f, 0.f, 0.f, 0.f};
    f32x4 lacc = {0.f, 0.f, 0.f, 0.f};        // l via MFMA: P * ones
    const int kread = (quad & 1) * 8;   // quad>=2 lanes duplicate (qa==0 there)

    short8 kreg = *(const short8*)(Kp);        // chunk 0
    short8 vreg = *(const short8*)(Vp);

    for (int it = 0; it < 8; ++it) {
        *(short8*)&Ks[key * 16 + half] = kreg;  // byte-linear: addr = tid*16B
        *(short8*)&Vt[dim * 136 + kc]  = vreg;
        if (it < 7) {                            // issue chunk it+1 pre-barrier
            kreg = *(const short8*)(Kp + (size_t)(it + 1) * 128 * 128);
            vreg = *(const short8*)(Vp + (it + 1) * 128);
        }
        __syncthreads();

        f32x4 s[8];
        f32x4 zc = {0.f, 0.f, 0.f, 0.f};
        #pragma unroll
        for (int g = 0; g < 8; ++g) {
            short8 kb = *(const short8*)&Ks[(g * 16 + l16) * 16 + kread];
            s[g] = __builtin_amdgcn_mfma_f32_16x16x32_bf16(kb, qa, zc, 0, 0, 0);  // swapped
        }

        #pragma unroll
        for (int t = 0; t < 4; ++t) {
            float p00 = fast_exp2(s[2*t][0]);
            float p01 = fast_exp2(s[2*t][1]);
            float p02 = fast_exp2(s[2*t][2]);
            float p03 = fast_exp2(s[2*t][3]);
            float p10 = fast_exp2(s[2*t+1][0]);
            float p11 = fast_exp2(s[2*t+1][1]);
            float p12 = fast_exp2(s[2*t+1][2]);
            float p13 = fast_exp2(s[2*t+1][3]);
            uint4 pk;
            pk.x = __builtin_amdgcn_perm(__builtin_bit_cast(unsigned, p01),
                                         __builtin_bit_cast(unsigned, p00), 0x07060302u);
            pk.y = __builtin_amdgcn_perm(__builtin_bit_cast(unsigned, p03),
                                         __builtin_bit_cast(unsigned, p02), 0x07060302u);
            pk.z = __builtin_amdgcn_perm(__builtin_bit_cast(unsigned, p11),
                                         __builtin_bit_cast(unsigned, p10), 0x07060302u);
            pk.w = __builtin_amdgcn_perm(__builtin_bit_cast(unsigned, p13),
                                         __builtin_bit_cast(unsigned, p12), 0x07060302u);
            short8 pa = __builtin_bit_cast(short8, pk);
            short8 vb = *(const short8*)&Vt[l16 * 136 + t * 32 + quad * 8];
            o    = __builtin_amdgcn_mfma_f32_16x16x32_bf16(pa, vb, o, 0, 0, 0);
            lacc = __builtin_amdgcn_mfma_f32_16x16x32_bf16(pa, onesv, lacc, 0, 0, 0);
        }
        if (it < 7) __syncthreads();   // all waves done reading Ks/Vt chunk it
    }

    #pragma unroll
    for (int r = 0; r < 4; ++r) {
        float linv = 1.0f / lacc[r];           // replicated across cols l16
        int qrow = q0 + wave * 16 + quad * 4 + r;
        Obh[((size_t)b * 1024 + qrow) * 128 + h * 16 + l16] = f2bf(o[r] * linv);
    }
}

// ---------------------------------------------------------------------------
extern "C" void kernel_launch(void* const* d_in, const int* in_sizes, int n_in,
                              void* d_out, int out_size, void* d_ws, size_t ws_size,
                              hipStream_t stream)
{
    const float* enc  = (const float*)d_in[0];
    const float* xraw = (const float*)d_in[2];
    const int*   ei   = (const int*)d_in[3];
    const float* Wg1  = (const float*)d_in[4];
    const float* bg1  = (const float*)d_in[5];
    const float* Wg2  = (const float*)d_in[6];
    const float* bg2  = (const float*)d_in[7];
    const float* Wq   = (const float*)d_in[8];
    const float* Wk   = (const float*)d_in[9];
    const float* Wv   = (const float*)d_in[10];
    const float* Wo   = (const float*)d_in[11];
    const float* Wff1 = (const float*)d_in[12];
    const float* bff1 = (const float*)d_in[13];
    const float* Wff2 = (const float*)d_in[14];
    const float* bff2 = (const float*)d_in[15];
    const float* ln1g = (const float*)d_in[16];
    const float* ln1b = (const float*)d_in[17];
    const float* ln2g = (const float*)d_in[18];
    const float* ln2b = (const float*)d_in[19];

    const int E  = in_sizes[3] / 2;            // 524288
    const int N  = in_sizes[2] / 128;          // 32768
    const int BM = in_sizes[0] / 128;          // 32768
    const int B  = BM / 1024;                  // 32
    const int L  = in_sizes[8] / (128 * 128);  // 2

    const int* srcE = ei;
    const int* dstE = ei + E;

    const size_t ND = (size_t)N * 128;         // 4194304

    // --- workspace layout: atomics at the BOTTOM; bufY 256B-ALIGNED ---
    float* ws   = (float*)d_ws;
    float* dinv = ws;                          // N f32
    int* cnt     = (int*)(ws + 32768);         // N
    int* csr_off = cnt + N;                    // N+1 (padded to N+4)
    int* cursor  = csr_off + N + 4;            // N
    int* csr_src = cursor + N;                 // E
    int* partial = csr_src + E;                // 128
    int* pbase   = partial + 128;              // 128
    float* bufY  = (float*)(((uintptr_t)(pbase + 128) + 255) & ~(uintptr_t)255);
    unsigned short* ush   = (unsigned short*)(bufY + ND);   // all 8MB-multiples after
    unsigned short* bufYh = ush;               // ND bf16 (residual shadow)
    unsigned short* bufBh = bufYh + ND;        // ND bf16 (GCN features / KV src)
    unsigned short* region = bufBh + ND;       // 4*ND bf16
    unsigned short* Qh  = region;              // ND   (transformer phase)
    unsigned short* Kg  = region + ND;         // ND  [b*1024+key][128]
    unsigned short* Vtg = region + 2 * ND;     // ND  [b,h,d][1024 slots]
    unsigned short* Th  = region + 3 * ND;     // ND (attn out)
    unsigned short* Hh  = region;              // FFN hidden (4*ND), overlaps
    unsigned char*  hsh8  = (unsigned char*)region;  // GCN fp8 h table (ND bytes, dead before Qh)
    unsigned short* xrawh = region + ND;       // x_raw bf16  (dead before Kg)
    unsigned short* wt  = region + 4 * ND;     // 425984 bf16 (workspace tail)

    // --- CSR + dinv (hierarchical scan) ---
    hipMemsetAsync(cnt, 0, (size_t)N * sizeof(int), stream);
    count_kernel<<<(E + 255) / 256, 256, 0, stream>>>(dstE, cnt, E);
    scanA_kernel<<<N / 256, 256, 0, stream>>>(cnt, partial);
    scanB_kernel<<<1, 128, 0, stream>>>(partial, pbase);
    scanC_kernel<<<N / 256, 256, 0, stream>>>(cnt, pbase, csr_off, cursor, dinv, N, E);
    place_kernel<<<(E + 255) / 256, 256, 0, stream>>>(srcE, dstE, cursor, csr_src, E);

    // --- fused converts + weight transpose (1 dispatch) ---
    const int nconv = (int)(ND / 1024);        // 4096
    prep_kernel<<<2 * nconv + 14 * 256, 256, 0, stream>>>(
        xraw, xrawh, enc, bufY, bufYh,
        Wg1, Wg2, Wq, Wk, Wv, Wo, Wff1, Wff2, wt, nconv);

    // --- GCN layer 1 (h table in fp8, x16) ---
    gemm64_kernel<<<dim3(N / 64, 2), 256, 0, stream>>>(xrawh, wt, hsh8, nullptr, 128,
        nullptr, dinv, 0, 3);
    gather_kernel<<<N / 4, 256, 0, stream>>>(hsh8, csr_off, csr_src, dinv, bg1, bufBh, N);
    // --- GCN layer 2 ---
    gemm64_kernel<<<dim3(N / 64, 2), 256, 0, stream>>>(bufBh, wt + 16384, hsh8, nullptr, 128,
        nullptr, dinv, 0, 3);
    gather_kernel<<<N / 4, 256, 0, stream>>>(hsh8, csr_off, csr_src, dinv, bg2, bufBh, N);
    // bufBh = GCN features (KV source)

    for (int l = 0; l < L; ++l) {
        const unsigned short* wtq  = wt + 32768  + (size_t)l * 16384;
        const unsigned short* wtkv = wt + 65536  + (size_t)l * 32768;
        const unsigned short* wto  = wt + 131072 + (size_t)l * 16384;
        const unsigned short* wtf1 = wt + 163840 + (size_t)l * 65536;
        const unsigned short* wtf2 = wt + 294912 + (size_t)l * 65536;

        // Q-proj + KV-proj fused (1 dispatch)
        qkv_kernel<<<dim3(BM / 64, 6), 256, 0, stream>>>(bufYh, wtq, Qh,
                                                         bufBh, wtkv, Kg, Vtg);

        attn_mfma_kernel<<<dim3(16, 8, B), 256, 0, stream>>>(Qh, Kg, Vtg, Th);

        // O-proj + residual + LN1 (fused), 32-row tiles
        gemm_ln_kernel<<<BM / 32, 256, 0, stream>>>(Th, wto, 128, nullptr,
            bufY, bufY, bufYh, ln1g + l * 128, ln1b + l * 128);

        gemm64_kernel<<<dim3(BM / 64, 8), 256, 0, stream>>>(bufYh, wtf1, Hh, nullptr, 128,
            bff1 + l * 512, nullptr, 1, 1);

        // FFN2 + residual + LN2 (fused), 32-row tiles; final layer -> d_out
        float* rout = (l == L - 1) ? (float*)d_out : bufY;
        gemm_ln_kernel<<<BM / 32, 256, 0, stream>>>(Hh, wtf2, 512, bff2 + l * 128,
            bufY, rout, bufYh, ln2g + l * 128, ln2b + l * 128);
    }
}

// Round 12
// 481.084 us; speedup vs baseline: 1.0133x; 1.0133x over previous
//
#include <hip/hip_runtime.h>
#include <math.h>

// GCN(2 layers, N=32768, E=524288, d=128) -> 2-layer cross-attention
// transformer (B=32, M=1024, d=128, H=8, dh=16, dff=512).
// R21: (1) gather reverted to R19 bf16 form — R19 (scalar idx, null) + R20
//   (fp8 rows, -5.7us regression) prove it's transaction-count-bound on
//   random rows; no more gather experiments. (2) ISOLATED gemm_ln
//   reg-prefetch (R11 bundled it with gemm64 and reverted both; never tested
//   alone): FFN2 K=512 has 8 serial K-iters x full load stall at 4 blk/CU.
//   Prefetch = 5 short8 regs (+20 VGPR, fits 128/wave budget), barriers
//   unchanged (2/iter), accumulation order bit-identical. (3) scanB folded
//   into scanC (per-block base via wave-reduce of partial[t<b]): -1 dispatch.
// R19 recap (481.8us): swapped-QK attn (52us floor), gemm64 R17-form 8wg/CU,
//   gemm_ln 32x128 4wg/CU, prep/qkv fused, bufY 256B-aligned, atomics bottom.

typedef __attribute__((ext_vector_type(8)))  short short8;   // 8 bf16 = 4 VGPRs
typedef __attribute__((ext_vector_type(4)))  float f32x4;
typedef __attribute__((ext_vector_type(16))) float f32x16;

__device__ __forceinline__ unsigned short f2bf(float x) {   // RNE fp32->bf16
    unsigned u = __builtin_bit_cast(unsigned, x);
    u = (u + 0x7FFFu + ((u >> 16) & 1u)) >> 16;
    return (unsigned short)u;
}
__device__ __forceinline__ float bflo(unsigned u) { return __builtin_bit_cast(float, u << 16); }
__device__ __forceinline__ float bfhi(unsigned u) { return __builtin_bit_cast(float, u & 0xffff0000u); }
__device__ __forceinline__ float fast_exp2(float x) {       // D = 2^S0
    float r; asm("v_exp_f32 %0, %1" : "=v"(r) : "v"(x)); return r;
}

// ---------------------------------------------------------------------------
// CSR build
// ---------------------------------------------------------------------------
__global__ void count_kernel(const int* __restrict__ dst, int* __restrict__ cnt, int E) {
    int e = blockIdx.x * 256 + threadIdx.x;
    if (e < E) atomicAdd(&cnt[dst[e]], 1);
}

// partial[b] = sum of cnt[b*256 .. b*256+255]
__global__ __launch_bounds__(256)
void scanA_kernel(const int* __restrict__ cnt, int* __restrict__ partial)
{
    __shared__ int wsum[4];
    int t = threadIdx.x;
    int v = cnt[blockIdx.x * 256 + t];
    #pragma unroll
    for (int off = 32; off; off >>= 1) v += __shfl_xor(v, off, 64);
    if ((t & 63) == 0) wsum[t >> 6] = v;
    __syncthreads();
    if (t == 0) partial[blockIdx.x] = wsum[0] + wsum[1] + wsum[2] + wsum[3];
}

// R21: scanB folded in — each block derives base = sum(partial[0..b-1]).
// off[i] = base + exclusive-scan-within-block; cursor = off; dinv = rsqrt
__global__ __launch_bounds__(256)
void scanC_kernel(const int* __restrict__ cnt, const int* __restrict__ partial,
                  int* __restrict__ off, int* __restrict__ cursor,
                  float* __restrict__ dinv, int N, int E)
{
    __shared__ int p[256];
    __shared__ int bsum[4];
    int t = threadIdx.x, b = blockIdx.x;
    int pv = (t < b) ? partial[t] : 0;      // b <= 127 < 128 entries
    #pragma unroll
    for (int o = 32; o; o >>= 1) pv += __shfl_xor(pv, o, 64);
    if ((t & 63) == 0) bsum[t >> 6] = pv;
    __syncthreads();
    const int base = bsum[0] + bsum[1] + bsum[2] + bsum[3];
    int i = b * 256 + t;
    int c = cnt[i];
    p[t] = c;
    __syncthreads();
    for (int o = 1; o < 256; o <<= 1) {
        int q = (t >= o) ? p[t - o] : 0;
        __syncthreads();
        p[t] += q;
        __syncthreads();
    }
    int ex = base + p[t] - c;
    off[i] = ex;
    cursor[i] = ex;
    dinv[i] = rsqrtf((float)c + 1.0f);
    if (b == 0 && t == 0) off[N] = E;
}

__global__ void place_kernel(const int* __restrict__ src, const int* __restrict__ dst,
                             int* __restrict__ cursor, int* __restrict__ csr_src, int E)
{
    int e = blockIdx.x * 256 + threadIdx.x;
    if (e < E) {
        int p = atomicAdd(&cursor[dst[e]], 1);
        csr_src[p] = src[e];
    }
}

// ---------------------------------------------------------------------------
// prep_kernel: fused conv(xraw->xrawh) | copyconv(enc->bufY,bufYh) | wtrans.
// Grid 1D: [0,nconv) conv, [nconv,2*nconv) copyconv, rest 256-block slots.
// Wq scale = 0.25 * log2(e): scores come out pre-multiplied for exp2.
// ---------------------------------------------------------------------------
__global__ __launch_bounds__(256)
void prep_kernel(const float* __restrict__ xraw, unsigned short* __restrict__ xrawh,
                 const float* __restrict__ enc, float* __restrict__ bufY,
                 unsigned short* __restrict__ bufYh,
                 const float* Wg1, const float* Wg2, const float* Wq, const float* Wk,
                 const float* Wv, const float* Wo, const float* Wff1, const float* Wff2,
                 unsigned short* __restrict__ out, int nconv)
{
    const int bid = blockIdx.x, tid = threadIdx.x;
    if (bid < nconv) {                       // conv: xraw -> xrawh (bf16)
        int i = bid * 256 + tid;
        float4 v = ((const float4*)xraw)[i];
        ushort4 h; h.x = f2bf(v.x); h.y = f2bf(v.y); h.z = f2bf(v.z); h.w = f2bf(v.w);
        ((ushort4*)xrawh)[i] = h;
        return;
    }
    if (bid < 2 * nconv) {                   // copyconv: enc -> bufY (f32) + bufYh
        int i = (bid - nconv) * 256 + tid;
        float4 v = ((const float4*)enc)[i];
        ((float4*)bufY)[i] = v;
        ushort4 h; h.x = f2bf(v.x); h.y = f2bf(v.y); h.z = f2bf(v.z); h.w = f2bf(v.w);
        ((ushort4*)bufYh)[i] = h;
        return;
    }
    const int bid2 = bid - 2 * nconv;
    const int slot = bid2 >> 8;              // 14 slots x 256 blocks
    const int bx   = bid2 & 255;
    const float* src; int ks; int Ns; size_t doff; float scale = 1.0f;
    if      (slot == 0)  { src = Wg1;                        ks = 7; Ns = 128; doff = 0; }
    else if (slot == 1)  { src = Wg2;                        ks = 7; Ns = 128; doff = 16384; }
    else if (slot <= 3)  { src = Wq  + (slot - 2)  * 16384;  ks = 7; Ns = 128; doff = 32768  + (size_t)(slot - 2)  * 16384; scale = 0.36067376022f; }
    else if (slot <= 5)  { src = Wk  + (slot - 4)  * 16384;  ks = 7; Ns = 128; doff = 65536  + (size_t)(slot - 4)  * 32768; }
    else if (slot <= 7)  { src = Wv  + (slot - 6)  * 16384;  ks = 7; Ns = 128; doff = 65536  + (size_t)(slot - 6)  * 32768 + 16384; }
    else if (slot <= 9)  { src = Wo  + (slot - 8)  * 16384;  ks = 7; Ns = 128; doff = 131072 + (size_t)(slot - 8)  * 16384; }
    else if (slot <= 11) { src = Wff1 + (slot - 10) * 65536; ks = 7; Ns = 512; doff = 163840 + (size_t)(slot - 10) * 65536; }
    else                 { src = Wff2 + (slot - 12) * 65536; ks = 9; Ns = 128; doff = 294912 + (size_t)(slot - 12) * 65536; }
    const int total = Ns << ks;
    int id = bx * 256 + tid;
    if (id >= total) return;
    int n = id >> ks;
    int k = id & ((1 << ks) - 1);
    out[doff + id] = f2bf(src[(size_t)k * Ns + n] * scale);
}

// ---------------------------------------------------------------------------
// gemm64_body: 64x64 tile, BK=64, 18.4 KB LDS -> 8 wg/CU (R17 form).
// Wave = one 32x32 MFMA tile. mode 1: bf16 out (+bias/relu/rowscale), ldc.
// mode 2: KV split (col<128 -> K natural; col>=128 -> V transposed [b,h,d,slot]
//         with slot mapping: key w=32t+16b+4qd+c -> slot=32t+8qd+4b+c).
// C/D: col=lane&31, row=(reg&3)+8*(reg>>2)+4*(lane>>5)  [verified mapping].
// ---------------------------------------------------------------------------
__device__ __forceinline__
void gemm64_body(unsigned short* As, unsigned short* Ws,
                 const unsigned short* __restrict__ A,
                 const unsigned short* __restrict__ Wt,
                 void* __restrict__ C, void* __restrict__ C2, int K, int ldc,
                 const float* __restrict__ bias, const float* __restrict__ rowscale,
                 int relu, int mode, int bx, int by)
{
    const int tid  = threadIdx.x;
    const int lane = tid & 63, wave = tid >> 6;
    const int m31 = lane & 31, hi = lane >> 5;
    const int row0 = bx * 64;
    const int c0   = by * 64;
    const int wrow = (wave & 1) * 32;
    const int wcol = (wave >> 1) * 32;
    const int sr = tid >> 2, sk = (tid & 3) * 16;

    f32x16 acc = {};

    for (int kt = 0; kt < K; kt += 64) {
        if (kt) __syncthreads();
        *(short8*)&As[sr * 72 + sk]     = *(const short8*)&A [(size_t)(row0 + sr) * K + kt + sk];
        *(short8*)&As[sr * 72 + sk + 8] = *(const short8*)&A [(size_t)(row0 + sr) * K + kt + sk + 8];
        *(short8*)&Ws[sr * 72 + sk]     = *(const short8*)&Wt[(size_t)(c0   + sr) * K + kt + sk];
        *(short8*)&Ws[sr * 72 + sk + 8] = *(const short8*)&Wt[(size_t)(c0   + sr) * K + kt + sk + 8];
        __syncthreads();
        #pragma unroll
        for (int ks = 0; ks < 4; ++ks) {
            short8 af = *(const short8*)&As[(wrow + m31) * 72 + ks * 16 + hi * 8];
            short8 bf = *(const short8*)&Ws[(wcol + m31) * 72 + ks * 16 + hi * 8];
            acc = __builtin_amdgcn_mfma_f32_32x32x16_bf16(af, bf, acc, 0, 0, 0);
        }
    }

    const int col = c0 + wcol + m31;
    #pragma unroll
    for (int r = 0; r < 16; ++r) {
        const int row = row0 + wrow + (r & 3) + 8 * (r >> 2) + 4 * hi;
        float v = acc[r];
        if (rowscale) v *= rowscale[row];
        if (bias) v += bias[col];
        if (relu) v = fmaxf(v, 0.0f);
        if (mode == 1) {
            ((unsigned short*)C)[(size_t)row * ldc + col] = f2bf(v);
        } else {    // KV: K natural (128 cols), V transposed [b,h,d,slot]
            if (col < 128) {
                ((unsigned short*)C)[(size_t)row * 128 + col] = f2bf(v);
            } else {
                int ch = col - 128, hh = ch >> 4, dd = ch & 15;
                int kg = row & 1023;                       // global key in batch
                int w  = kg & 127;                         // within 128-chunk
                // slot: w = 32t+16b+4qd+c -> slot = 32t+8qd+4b+c
                int slot = ((w >> 5) << 5) | (((w >> 2) & 3) << 3)
                         | (((w >> 4) & 1) << 2) | (w & 3);
                int kpos = (kg & ~127) | slot;
                ((unsigned short*)C2)[(((size_t)(row >> 10) * 8 + hh) * 16 + dd) * 1024
                                      + kpos] = f2bf(v);
            }
        }
    }
}

__global__ __launch_bounds__(256)
void gemm64_kernel(const unsigned short* __restrict__ A,
                   const unsigned short* __restrict__ Wt,
                   void* __restrict__ C, void* __restrict__ C2, int K,
                   const float* __restrict__ bias, const float* __restrict__ rowscale,
                   int relu, int mode)
{
    __shared__ unsigned short As[64 * 72];
    __shared__ unsigned short Ws[64 * 72];
    gemm64_body(As, Ws, A, Wt, C, C2, K, gridDim.y * 64, bias, rowscale, relu, mode,
                blockIdx.x, blockIdx.y);
}

// Q-proj (y<2) + KV-proj (y in 2..5) in one dispatch. Branch is block-uniform.
__global__ __launch_bounds__(256)
void qkv_kernel(const unsigned short* __restrict__ Yh, const unsigned short* __restrict__ wtq,
                unsigned short* __restrict__ Qh,
                const unsigned short* __restrict__ Bh, const unsigned short* __restrict__ wtkv,
                unsigned short* __restrict__ Kg, unsigned short* __restrict__ Vtg)
{
    __shared__ unsigned short As[64 * 72];
    __shared__ unsigned short Ws[64 * 72];
    if (blockIdx.y < 2)
        gemm64_body(As, Ws, Yh, wtq, Qh, nullptr, 128, 128, nullptr, nullptr, 0, 1,
                    blockIdx.x, blockIdx.y);
    else
        gemm64_body(As, Ws, Bh, wtkv, Kg, Vtg, 128, 256, nullptr, nullptr, 0, 2,
                    blockIdx.x, blockIdx.y - 2);
}

// ---------------------------------------------------------------------------
// gemm_ln: 32x128 tile, BK=64; per-wave 32x32 (one f32x16 acc).
// Grid BM/32 = 1024 blocks; LDS 23.0 KB -> 4 blocks/CU.
// R21: reg-prefetch K-loop (isolated; R11 never tested gemm_ln alone):
// LDS written from regs loaded one compute-phase earlier, next chunk issued
// pre-barrier -> the per-iteration global-load stall (8 iters at K=512)
// hides under MFMAs. Barriers 2/iter (unchanged), accumulation bit-identical.
// Epilogue = bias + residual + LayerNorm; writes resid_out f32 + yh bf16.
// LDS reused as f32 stash [32][130]. LN row = 8 threads x 16 cols.
// ---------------------------------------------------------------------------
__global__ __launch_bounds__(256)
void gemm_ln_kernel(const unsigned short* __restrict__ A,
                    const unsigned short* __restrict__ Wt, int K,
                    const float* __restrict__ bias,
                    const float* __restrict__ resid_in, float* __restrict__ resid_out,
                    unsigned short* __restrict__ yh,
                    const float* __restrict__ lng, const float* __restrict__ lnb)
{
    __shared__ __align__(16) unsigned char smraw[23040];  // As[32][72] 4608 | Ws[128][72] 18432
    unsigned short* As = (unsigned short*)smraw;           // [32][72]
    unsigned short* Ws = (unsigned short*)(smraw + 4608);  // [128][72]

    const int tid  = threadIdx.x;
    const int lane = tid & 63, wave = tid >> 6;
    const int m31 = lane & 31, hi = lane >> 5;
    const int row0 = blockIdx.x * 32;
    const int wcol = wave * 32;                     // wave owns cols wcol..wcol+31
    const int sr = tid >> 3, sk = (tid & 7) * 8;    // A staging: 32 rows x 8 slots
    const int wr = tid >> 1, wo = (tid & 1) * 32;   // W staging: 128 rows x 2 halves

    const unsigned short* Ap = &A [(size_t)(row0 + sr) * K + sk];
    const unsigned short* Wp = &Wt[(size_t)wr * K + wo];

    short8 ra0 = *(const short8*)(Ap);
    short8 rw0 = *(const short8*)(Wp);
    short8 rw1 = *(const short8*)(Wp + 8);
    short8 rw2 = *(const short8*)(Wp + 16);
    short8 rw3 = *(const short8*)(Wp + 24);

    f32x16 acc = {};

    for (int kt = 0; kt < K; kt += 64) {
        *(short8*)&As[sr * 72 + sk]      = ra0;   // vmcnt wait hidden (issued one
        *(short8*)&Ws[wr * 72 + wo]      = rw0;   // compute-phase ago)
        *(short8*)&Ws[wr * 72 + wo + 8]  = rw1;
        *(short8*)&Ws[wr * 72 + wo + 16] = rw2;
        *(short8*)&Ws[wr * 72 + wo + 24] = rw3;
        if (kt + 64 < K) {                         // issue next chunk pre-barrier
            ra0 = *(const short8*)(Ap + kt + 64);
            rw0 = *(const short8*)(Wp + kt + 64);
            rw1 = *(const short8*)(Wp + kt + 72);
            rw2 = *(const short8*)(Wp + kt + 80);
            rw3 = *(const short8*)(Wp + kt + 88);
        }
        __syncthreads();
        #pragma unroll
        for (int ks = 0; ks < 4; ++ks) {
            short8 af = *(const short8*)&As[m31 * 72 + ks * 16 + hi * 8];
            short8 bf = *(const short8*)&Ws[(wcol + m31) * 72 + ks * 16 + hi * 8];
            acc = __builtin_amdgcn_mfma_f32_32x32x16_bf16(af, bf, acc, 0, 0, 0);
        }
        __syncthreads();   // readers done; also fences last iter before stash
    }

    // --- stash t into LDS, then per-row residual + LN ---
    float* Ts = (float*)smraw;    // [32][130]
    {
        const int col = wcol + m31;
        #pragma unroll
        for (int r = 0; r < 16; ++r) {
            const int rl = (r & 3) + 8 * (r >> 2) + 4 * hi;
            float v = acc[r];
            if (bias) v += bias[col];
            Ts[rl * 130 + col] = v;
        }
    }
    __syncthreads();
    const int r  = tid >> 3;       // 0..31
    const int cq = tid & 7;        // 8 threads per row, 16 cols each
    const int row = row0 + r;
    float v[16], s1 = 0.f, s2 = 0.f;
    const float* yr = resid_in + (size_t)row * 128 + cq * 16;
    #pragma unroll
    for (int i = 0; i < 4; ++i) {
        float4 yv = *(const float4*)&yr[i * 4];
        float ys[4] = {yv.x, yv.y, yv.z, yv.w};
        #pragma unroll
        for (int j = 0; j < 4; ++j) {
            float t = Ts[r * 130 + cq * 16 + i * 4 + j] + ys[j];
            v[i * 4 + j] = t; s1 += t; s2 += t * t;
        }
    }
    s1 += __shfl_xor(s1, 1, 64); s1 += __shfl_xor(s1, 2, 64); s1 += __shfl_xor(s1, 4, 64);
    s2 += __shfl_xor(s2, 1, 64); s2 += __shfl_xor(s2, 2, 64); s2 += __shfl_xor(s2, 4, 64);
    const float mu  = s1 * (1.0f / 128.0f);
    const float inv = rsqrtf(s2 * (1.0f / 128.0f) - mu * mu + 1e-5f);
    float* outr = resid_out + (size_t)row * 128 + cq * 16;
    unsigned short* yhr = yh + (size_t)row * 128 + cq * 16;
    #pragma unroll
    for (int i = 0; i < 4; ++i) {
        float o0 = (v[i*4+0] - mu) * inv * lng[cq*16 + i*4 + 0] + lnb[cq*16 + i*4 + 0];
        float o1 = (v[i*4+1] - mu) * inv * lng[cq*16 + i*4 + 1] + lnb[cq*16 + i*4 + 1];
        float o2 = (v[i*4+2] - mu) * inv * lng[cq*16 + i*4 + 2] + lnb[cq*16 + i*4 + 2];
        float o3 = (v[i*4+3] - mu) * inv * lng[cq*16 + i*4 + 3] + lnb[cq*16 + i*4 + 3];
        float4 ov; ov.x = o0; ov.y = o1; ov.z = o2; ov.w = o3;
        *(float4*)&outr[i * 4] = ov;
        ushort4 hv; hv.x = f2bf(o0); hv.y = f2bf(o1); hv.z = f2bf(o2); hv.w = f2bf(o3);
        *(ushort4*)&yhr[i * 4] = hv;
    }
}

// ---------------------------------------------------------------------------
// GCN gather (bf16 in/out): one wave per node, 2 channels per lane.
// (R19 form: scalar neighbor indices, 4-deep load window. R20's fp8 rows
// regressed — transaction-count-bound, not byte-bound.)
// ---------------------------------------------------------------------------
__global__ __launch_bounds__(256)
void gather_kernel(const unsigned short* __restrict__ hs, const int* __restrict__ csr_off,
                   const int* __restrict__ csr_src, const float* __restrict__ dinv,
                   const float* __restrict__ bias, unsigned short* __restrict__ out, int N)
{
    const int node = blockIdx.x * 4 + (threadIdx.x >> 6);
    const int lane = threadIdx.x & 63;
    const int s0 = __builtin_amdgcn_readfirstlane(csr_off[node]);
    const int s1 = __builtin_amdgcn_readfirstlane(csr_off[node + 1]);
    const unsigned* hsu = (const unsigned*)hs;

    unsigned u = hsu[(size_t)node * 64 + lane];
    float a0 = bflo(u), a1 = bfhi(u);

    int j = s0;
    for (; j + 4 <= s1; j += 4) {
        int i0 = csr_src[j];        // wave-uniform -> scalar pipe
        int i1 = csr_src[j + 1];
        int i2 = csr_src[j + 2];
        int i3 = csr_src[j + 3];
        unsigned uA = hsu[(size_t)i0 * 64 + lane];
        unsigned uB = hsu[(size_t)i1 * 64 + lane];
        unsigned uC = hsu[(size_t)i2 * 64 + lane];
        unsigned uD = hsu[(size_t)i3 * 64 + lane];
        a0 += (bflo(uA) + bflo(uB)) + (bflo(uC) + bflo(uD));
        a1 += (bfhi(uA) + bfhi(uB)) + (bfhi(uC) + bfhi(uD));
    }
    for (; j < s1; ++j) {
        int ib = csr_src[j];
        unsigned ub = hsu[(size_t)ib * 64 + lane];
        a0 += bflo(ub); a1 += bfhi(ub);
    }
    float di = dinv[node];
    float v0 = fmaxf(a0 * di + bias[lane * 2],     0.0f);
    float v1 = fmaxf(a1 * di + bias[lane * 2 + 1], 0.0f);
    ((unsigned*)out)[(size_t)node * 64 + lane] =
        ((unsigned)f2bf(v1) << 16) | (unsigned)f2bf(v0);
}

// ---------------------------------------------------------------------------
// MFMA flash cross-attention. Block = (64q, head, batch), wave owns 16 q,
// 128-key chunks. Ks natural [128 keys][16 dims] (4KB), byte-linear staging.
// SWAPPED QK^T: s[g] = mfma(kb, qa) -> lane (quad,l16) holds scores for
// q=l16, keys {16g+4quad+r}. exp + pack feed PV's A-fragment directly
// (P[q=l16][slot quad*8+j], slot->key = 32t+16(j>>2)+4quad+(j&3)); Vtg is
// pre-permuted to this slot order by the KV GEMM. No P LDS. quad>=2 lanes:
// qa=0 (B zero) x kb-garbage (finite) = 0 for k=16..31. l = P*ones via MFMA.
// ---------------------------------------------------------------------------
__global__ __launch_bounds__(256)
void attn_mfma_kernel(const unsigned short* __restrict__ Qh,
                      const unsigned short* __restrict__ Kg,
                      const unsigned short* __restrict__ Vtg,
                      unsigned short* __restrict__ Obh)
{
    __shared__ __align__(16) unsigned short Ks[128 * 16];  // [key][dim 0..15]
    __shared__ __align__(16) unsigned short Vt[16 * 136];  // [dim][slot 0..127]

    const int tid  = threadIdx.x;
    const int lane = tid & 63, wave = tid >> 6;
    const int quad = lane >> 4, l16 = lane & 15;
    const int q0 = blockIdx.x * 64, h = blockIdx.y, b = blockIdx.z;

    // staging coords (fixed per thread)
    const int key  = tid >> 1, half = (tid & 1) * 8;
    const int dim  = tid >> 4, kc = (tid & 15) * 8;
    const unsigned short* Kp = &Kg[((size_t)b * 1024 + key) * 128 + h * 16 + half];
    const unsigned short* Vp = &Vtg[(((size_t)b * 8 + h) * 16 + dim) * 1024 + kc];

    short8 qa = {};
    if (quad < 2) {
        qa = *(const short8*)&Qh[((size_t)b * 1024 + q0 + wave * 16 + l16) * 128 + h * 16 + quad * 8];
    }

    const short one_bf = (short)0x3F80;       // bf16 1.0
    const short8 onesv = {one_bf, one_bf, one_bf, one_bf,
                          one_bf, one_bf, one_bf, one_bf};

    f32x4 o    = {0.f, 0.f, 0.f, 0.f};
    f32x4 lacc = {0.f, 0.f, 0.f, 0.f};        // l via MFMA: P * ones
    const int kread = (quad & 1) * 8;   // quad>=2 lanes duplicate (qa==0 there)

    short8 kreg = *(const short8*)(Kp);        // chunk 0
    short8 vreg = *(const short8*)(Vp);

    for (int it = 0; it < 8; ++it) {
        *(short8*)&Ks[key * 16 + half] = kreg;  // byte-linear: addr = tid*16B
        *(short8*)&Vt[dim * 136 + kc]  = vreg;
        if (it < 7) {                            // issue chunk it+1 pre-barrier
            kreg = *(const short8*)(Kp + (size_t)(it + 1) * 128 * 128);
            vreg = *(const short8*)(Vp + (it + 1) * 128);
        }
        __syncthreads();

        f32x4 s[8];
        f32x4 zc = {0.f, 0.f, 0.f, 0.f};
        #pragma unroll
        for (int g = 0; g < 8; ++g) {
            short8 kb = *(const short8*)&Ks[(g * 16 + l16) * 16 + kread];
            s[g] = __builtin_amdgcn_mfma_f32_16x16x32_bf16(kb, qa, zc, 0, 0, 0);  // swapped
        }

        #pragma unroll
        for (int t = 0; t < 4; ++t) {
            float p00 = fast_exp2(s[2*t][0]);
            float p01 = fast_exp2(s[2*t][1]);
            float p02 = fast_exp2(s[2*t][2]);
            float p03 = fast_exp2(s[2*t][3]);
            float p10 = fast_exp2(s[2*t+1][0]);
            float p11 = fast_exp2(s[2*t+1][1]);
            float p12 = fast_exp2(s[2*t+1][2]);
            float p13 = fast_exp2(s[2*t+1][3]);
            uint4 pk;
            pk.x = __builtin_amdgcn_perm(__builtin_bit_cast(unsigned, p01),
                                         __builtin_bit_cast(unsigned, p00), 0x07060302u);
            pk.y = __builtin_amdgcn_perm(__builtin_bit_cast(unsigned, p03),
                                         __builtin_bit_cast(unsigned, p02), 0x07060302u);
            pk.z = __builtin_amdgcn_perm(__builtin_bit_cast(unsigned, p11),
                                         __builtin_bit_cast(unsigned, p10), 0x07060302u);
            pk.w = __builtin_amdgcn_perm(__builtin_bit_cast(unsigned, p13),
                                         __builtin_bit_cast(unsigned, p12), 0x07060302u);
            short8 pa = __builtin_bit_cast(short8, pk);
            short8 vb = *(const short8*)&Vt[l16 * 136 + t * 32 + quad * 8];
            o    = __builtin_amdgcn_mfma_f32_16x16x32_bf16(pa, vb, o, 0, 0, 0);
            lacc = __builtin_amdgcn_mfma_f32_16x16x32_bf16(pa, onesv, lacc, 0, 0, 0);
        }
        if (it < 7) __syncthreads();   // all waves done reading Ks/Vt chunk it
    }

    #pragma unroll
    for (int r = 0; r < 4; ++r) {
        float linv = 1.0f / lacc[r];           // replicated across cols l16
        int qrow = q0 + wave * 16 + quad * 4 + r;
        Obh[((size_t)b * 1024 + qrow) * 128 + h * 16 + l16] = f2bf(o[r] * linv);
    }
}

// ---------------------------------------------------------------------------
extern "C" void kernel_launch(void* const* d_in, const int* in_sizes, int n_in,
                              void* d_out, int out_size, void* d_ws, size_t ws_size,
                              hipStream_t stream)
{
    const float* enc  = (const float*)d_in[0];
    const float* xraw = (const float*)d_in[2];
    const int*   ei   = (const int*)d_in[3];
    const float* Wg1  = (const float*)d_in[4];
    const float* bg1  = (const float*)d_in[5];
    const float* Wg2  = (const float*)d_in[6];
    const float* bg2  = (const float*)d_in[7];
    const float* Wq   = (const float*)d_in[8];
    const float* Wk   = (const float*)d_in[9];
    const float* Wv   = (const float*)d_in[10];
    const float* Wo   = (const float*)d_in[11];
    const float* Wff1 = (const float*)d_in[12];
    const float* bff1 = (const float*)d_in[13];
    const float* Wff2 = (const float*)d_in[14];
    const float* bff2 = (const float*)d_in[15];
    const float* ln1g = (const float*)d_in[16];
    const float* ln1b = (const float*)d_in[17];
    const float* ln2g = (const float*)d_in[18];
    const float* ln2b = (const float*)d_in[19];

    const int E  = in_sizes[3] / 2;            // 524288
    const int N  = in_sizes[2] / 128;          // 32768
    const int BM = in_sizes[0] / 128;          // 32768
    const int B  = BM / 1024;                  // 32
    const int L  = in_sizes[8] / (128 * 128);  // 2

    const int* srcE = ei;
    const int* dstE = ei + E;

    const size_t ND = (size_t)N * 128;         // 4194304

    // --- workspace layout: atomics at the BOTTOM; bufY 256B-ALIGNED ---
    float* ws   = (float*)d_ws;
    float* dinv = ws;                          // N f32
    int* cnt     = (int*)(ws + 32768);         // N
    int* csr_off = cnt + N;                    // N+1 (padded to N+4)
    int* cursor  = csr_off + N + 4;            // N
    int* csr_src = cursor + N;                 // E
    int* partial = csr_src + E;                // 128
    int* pbase   = partial + 128;              // 128 (unused, layout keeper)
    float* bufY  = (float*)(((uintptr_t)(pbase + 128) + 255) & ~(uintptr_t)255);
    unsigned short* ush   = (unsigned short*)(bufY + ND);   // all 8MB-multiples after
    unsigned short* bufYh = ush;               // ND bf16 (residual shadow)
    unsigned short* bufBh = bufYh + ND;        // ND bf16 (GCN features / KV src)
    unsigned short* region = bufBh + ND;       // 4*ND bf16
    unsigned short* Qh  = region;              // ND   (transformer phase)
    unsigned short* Kg  = region + ND;         // ND  [b*1024+key][128]
    unsigned short* Vtg = region + 2 * ND;     // ND  [b,h,d][1024 slots]
    unsigned short* Th  = region + 3 * ND;     // ND (attn out)
    unsigned short* Hh  = region;              // FFN hidden (4*ND), overlaps
    unsigned short* hsh   = region;            // GCN gemm out (dead before Qh)
    unsigned short* xrawh = region + ND;       // x_raw bf16  (dead before Kg)
    unsigned short* wt  = region + 4 * ND;     // 425984 bf16 (workspace tail)

    // --- CSR + dinv (hierarchical scan; scanB folded into scanC) ---
    hipMemsetAsync(cnt, 0, (size_t)N * sizeof(int), stream);
    count_kernel<<<(E + 255) / 256, 256, 0, stream>>>(dstE, cnt, E);
    scanA_kernel<<<N / 256, 256, 0, stream>>>(cnt, partial);
    scanC_kernel<<<N / 256, 256, 0, stream>>>(cnt, partial, csr_off, cursor, dinv, N, E);
    place_kernel<<<(E + 255) / 256, 256, 0, stream>>>(srcE, dstE, cursor, csr_src, E);

    // --- fused converts + weight transpose (1 dispatch) ---
    const int nconv = (int)(ND / 1024);        // 4096
    prep_kernel<<<2 * nconv + 14 * 256, 256, 0, stream>>>(
        xraw, xrawh, enc, bufY, bufYh,
        Wg1, Wg2, Wq, Wk, Wv, Wo, Wff1, Wff2, wt, nconv);

    // --- GCN layer 1 ---
    gemm64_kernel<<<dim3(N / 64, 2), 256, 0, stream>>>(xrawh, wt, hsh, nullptr, 128,
        nullptr, dinv, 0, 1);
    gather_kernel<<<N / 4, 256, 0, stream>>>(hsh, csr_off, csr_src, dinv, bg1, bufBh, N);
    // --- GCN layer 2 ---
    gemm64_kernel<<<dim3(N / 64, 2), 256, 0, stream>>>(bufBh, wt + 16384, hsh, nullptr, 128,
        nullptr, dinv, 0, 1);
    gather_kernel<<<N / 4, 256, 0, stream>>>(hsh, csr_off, csr_src, dinv, bg2, bufBh, N);
    // bufBh = GCN features (KV source)

    for (int l = 0; l < L; ++l) {
        const unsigned short* wtq  = wt + 32768  + (size_t)l * 16384;
        const unsigned short* wtkv = wt + 65536  + (size_t)l * 32768;
        const unsigned short* wto  = wt + 131072 + (size_t)l * 16384;
        const unsigned short* wtf1 = wt + 163840 + (size_t)l * 65536;
        const unsigned short* wtf2 = wt + 294912 + (size_t)l * 65536;

        // Q-proj + KV-proj fused (1 dispatch)
        qkv_kernel<<<dim3(BM / 64, 6), 256, 0, stream>>>(bufYh, wtq, Qh,
                                                         bufBh, wtkv, Kg, Vtg);

        attn_mfma_kernel<<<dim3(16, 8, B), 256, 0, stream>>>(Qh, Kg, Vtg, Th);

        // O-proj + residual + LN1 (fused), 32-row tiles
        gemm_ln_kernel<<<BM / 32, 256, 0, stream>>>(Th, wto, 128, nullptr,
            bufY, bufY, bufYh, ln1g + l * 128, ln1b + l * 128);

        gemm64_kernel<<<dim3(BM / 64, 8), 256, 0, stream>>>(bufYh, wtf1, Hh, nullptr, 128,
            bff1 + l * 512, nullptr, 1, 1);

        // FFN2 + residual + LN2 (fused), 32-row tiles; final layer -> d_out
        float* rout = (l == L - 1) ? (float*)d_out : bufY;
        gemm_ln_kernel<<<BM / 32, 256, 0, stream>>>(Hh, wtf2, 512, bff2 + l * 128,
            bufY, rout, bufYh, ln2g + l * 128, ln2b + l * 128);
    }
}

// Round 13
// 464.495 us; speedup vs baseline: 1.0495x; 1.0357x over previous
//
#include <hip/hip_runtime.h>
#include <math.h>

// GCN(2 layers, N=32768, E=524288, d=128) -> 2-layer cross-attention
// transformer (B=32, M=1024, d=128, H=8, dh=16, dff=512).
// R22: (1) bf16 RESIDUAL: bufY (f32 residual master) dropped entirely; bufYh
//   is the sole residual. LN recomputes from t+resid each stage so bf16 resid
//   rounding (~0.004 abs) is non-compounding; predicted absmax <=0.05 (thr
//   0.095). Saves ~110MB HBM: gemm_ln resid read 16->8MB, f32 write 16->0
//   (except final d_out), prep's bufY write dropped. (2) attn LDS double-
//   buffer: Ks/Vt x2 (17KB, occupancy unchanged at 40 VGPR), barriers/chunk
//   2->1 (15->8 per dispatch). attn is exp2-transcendental-bound (~50.7us
//   floor, 268M v_exp at quarter rate = 54us) — this trims barrier drains.
// R21 recap (481.1us): swapped-QK attn, gemm64 R17-form 8wg/CU, gemm_ln
//   32x128 + reg-prefetch, scalar-idx gather, scanB folded, prep/qkv fused.

typedef __attribute__((ext_vector_type(8)))  short short8;   // 8 bf16 = 4 VGPRs
typedef __attribute__((ext_vector_type(4)))  float f32x4;
typedef __attribute__((ext_vector_type(16))) float f32x16;

__device__ __forceinline__ unsigned short f2bf(float x) {   // RNE fp32->bf16
    unsigned u = __builtin_bit_cast(unsigned, x);
    u = (u + 0x7FFFu + ((u >> 16) & 1u)) >> 16;
    return (unsigned short)u;
}
__device__ __forceinline__ float bflo(unsigned u) { return __builtin_bit_cast(float, u << 16); }
__device__ __forceinline__ float bfhi(unsigned u) { return __builtin_bit_cast(float, u & 0xffff0000u); }
__device__ __forceinline__ float fast_exp2(float x) {       // D = 2^S0
    float r; asm("v_exp_f32 %0, %1" : "=v"(r) : "v"(x)); return r;
}

// ---------------------------------------------------------------------------
// CSR build
// ---------------------------------------------------------------------------
__global__ void count_kernel(const int* __restrict__ dst, int* __restrict__ cnt, int E) {
    int e = blockIdx.x * 256 + threadIdx.x;
    if (e < E) atomicAdd(&cnt[dst[e]], 1);
}

// partial[b] = sum of cnt[b*256 .. b*256+255]
__global__ __launch_bounds__(256)
void scanA_kernel(const int* __restrict__ cnt, int* __restrict__ partial)
{
    __shared__ int wsum[4];
    int t = threadIdx.x;
    int v = cnt[blockIdx.x * 256 + t];
    #pragma unroll
    for (int off = 32; off; off >>= 1) v += __shfl_xor(v, off, 64);
    if ((t & 63) == 0) wsum[t >> 6] = v;
    __syncthreads();
    if (t == 0) partial[blockIdx.x] = wsum[0] + wsum[1] + wsum[2] + wsum[3];
}

// scanB folded in — each block derives base = sum(partial[0..b-1]).
// off[i] = base + exclusive-scan-within-block; cursor = off; dinv = rsqrt
__global__ __launch_bounds__(256)
void scanC_kernel(const int* __restrict__ cnt, const int* __restrict__ partial,
                  int* __restrict__ off, int* __restrict__ cursor,
                  float* __restrict__ dinv, int N, int E)
{
    __shared__ int p[256];
    __shared__ int bsum[4];
    int t = threadIdx.x, b = blockIdx.x;
    int pv = (t < b) ? partial[t] : 0;      // b <= 127 < 128 entries
    #pragma unroll
    for (int o = 32; o; o >>= 1) pv += __shfl_xor(pv, o, 64);
    if ((t & 63) == 0) bsum[t >> 6] = pv;
    __syncthreads();
    const int base = bsum[0] + bsum[1] + bsum[2] + bsum[3];
    int i = b * 256 + t;
    int c = cnt[i];
    p[t] = c;
    __syncthreads();
    for (int o = 1; o < 256; o <<= 1) {
        int q = (t >= o) ? p[t - o] : 0;
        __syncthreads();
        p[t] += q;
        __syncthreads();
    }
    int ex = base + p[t] - c;
    off[i] = ex;
    cursor[i] = ex;
    dinv[i] = rsqrtf((float)c + 1.0f);
    if (b == 0 && t == 0) off[N] = E;
}

__global__ void place_kernel(const int* __restrict__ src, const int* __restrict__ dst,
                             int* __restrict__ cursor, int* __restrict__ csr_src, int E)
{
    int e = blockIdx.x * 256 + threadIdx.x;
    if (e < E) {
        int p = atomicAdd(&cursor[dst[e]], 1);
        csr_src[p] = src[e];
    }
}

// ---------------------------------------------------------------------------
// prep_kernel: fused conv(xraw->xrawh) | conv(enc->bufYh) | wtrans.
// (R22: enc's f32 copy dropped — bf16 residual only.)
// Wq scale = 0.25 * log2(e): scores come out pre-multiplied for exp2.
// ---------------------------------------------------------------------------
__global__ __launch_bounds__(256)
void prep_kernel(const float* __restrict__ xraw, unsigned short* __restrict__ xrawh,
                 const float* __restrict__ enc, unsigned short* __restrict__ bufYh,
                 const float* Wg1, const float* Wg2, const float* Wq, const float* Wk,
                 const float* Wv, const float* Wo, const float* Wff1, const float* Wff2,
                 unsigned short* __restrict__ out, int nconv)
{
    const int bid = blockIdx.x, tid = threadIdx.x;
    if (bid < 2 * nconv) {                   // conv: xraw->xrawh | enc->bufYh
        const float* s = (bid < nconv) ? xraw : enc;
        unsigned short* d = (bid < nconv) ? xrawh : bufYh;
        int i = ((bid < nconv) ? bid : bid - nconv) * 256 + tid;
        float4 v = ((const float4*)s)[i];
        ushort4 h; h.x = f2bf(v.x); h.y = f2bf(v.y); h.z = f2bf(v.z); h.w = f2bf(v.w);
        ((ushort4*)d)[i] = h;
        return;
    }
    const int bid2 = bid - 2 * nconv;
    const int slot = bid2 >> 8;              // 14 slots x 256 blocks
    const int bx   = bid2 & 255;
    const float* src; int ks; int Ns; size_t doff; float scale = 1.0f;
    if      (slot == 0)  { src = Wg1;                        ks = 7; Ns = 128; doff = 0; }
    else if (slot == 1)  { src = Wg2;                        ks = 7; Ns = 128; doff = 16384; }
    else if (slot <= 3)  { src = Wq  + (slot - 2)  * 16384;  ks = 7; Ns = 128; doff = 32768  + (size_t)(slot - 2)  * 16384; scale = 0.36067376022f; }
    else if (slot <= 5)  { src = Wk  + (slot - 4)  * 16384;  ks = 7; Ns = 128; doff = 65536  + (size_t)(slot - 4)  * 32768; }
    else if (slot <= 7)  { src = Wv  + (slot - 6)  * 16384;  ks = 7; Ns = 128; doff = 65536  + (size_t)(slot - 6)  * 32768 + 16384; }
    else if (slot <= 9)  { src = Wo  + (slot - 8)  * 16384;  ks = 7; Ns = 128; doff = 131072 + (size_t)(slot - 8)  * 16384; }
    else if (slot <= 11) { src = Wff1 + (slot - 10) * 65536; ks = 7; Ns = 512; doff = 163840 + (size_t)(slot - 10) * 65536; }
    else                 { src = Wff2 + (slot - 12) * 65536; ks = 9; Ns = 128; doff = 294912 + (size_t)(slot - 12) * 65536; }
    const int total = Ns << ks;
    int id = bx * 256 + tid;
    if (id >= total) return;
    int n = id >> ks;
    int k = id & ((1 << ks) - 1);
    out[doff + id] = f2bf(src[(size_t)k * Ns + n] * scale);
}

// ---------------------------------------------------------------------------
// gemm64_body: 64x64 tile, BK=64, 18.4 KB LDS -> 8 wg/CU (R17 form).
// Wave = one 32x32 MFMA tile. mode 1: bf16 out (+bias/relu/rowscale), ldc.
// mode 2: KV split (col<128 -> K natural; col>=128 -> V transposed [b,h,d,slot]
//         with slot mapping: key w=32t+16b+4qd+c -> slot=32t+8qd+4b+c).
// C/D: col=lane&31, row=(reg&3)+8*(reg>>2)+4*(lane>>5)  [verified mapping].
// ---------------------------------------------------------------------------
__device__ __forceinline__
void gemm64_body(unsigned short* As, unsigned short* Ws,
                 const unsigned short* __restrict__ A,
                 const unsigned short* __restrict__ Wt,
                 void* __restrict__ C, void* __restrict__ C2, int K, int ldc,
                 const float* __restrict__ bias, const float* __restrict__ rowscale,
                 int relu, int mode, int bx, int by)
{
    const int tid  = threadIdx.x;
    const int lane = tid & 63, wave = tid >> 6;
    const int m31 = lane & 31, hi = lane >> 5;
    const int row0 = bx * 64;
    const int c0   = by * 64;
    const int wrow = (wave & 1) * 32;
    const int wcol = (wave >> 1) * 32;
    const int sr = tid >> 2, sk = (tid & 3) * 16;

    f32x16 acc = {};

    for (int kt = 0; kt < K; kt += 64) {
        if (kt) __syncthreads();
        *(short8*)&As[sr * 72 + sk]     = *(const short8*)&A [(size_t)(row0 + sr) * K + kt + sk];
        *(short8*)&As[sr * 72 + sk + 8] = *(const short8*)&A [(size_t)(row0 + sr) * K + kt + sk + 8];
        *(short8*)&Ws[sr * 72 + sk]     = *(const short8*)&Wt[(size_t)(c0   + sr) * K + kt + sk];
        *(short8*)&Ws[sr * 72 + sk + 8] = *(const short8*)&Wt[(size_t)(c0   + sr) * K + kt + sk + 8];
        __syncthreads();
        #pragma unroll
        for (int ks = 0; ks < 4; ++ks) {
            short8 af = *(const short8*)&As[(wrow + m31) * 72 + ks * 16 + hi * 8];
            short8 bf = *(const short8*)&Ws[(wcol + m31) * 72 + ks * 16 + hi * 8];
            acc = __builtin_amdgcn_mfma_f32_32x32x16_bf16(af, bf, acc, 0, 0, 0);
        }
    }

    const int col = c0 + wcol + m31;
    #pragma unroll
    for (int r = 0; r < 16; ++r) {
        const int row = row0 + wrow + (r & 3) + 8 * (r >> 2) + 4 * hi;
        float v = acc[r];
        if (rowscale) v *= rowscale[row];
        if (bias) v += bias[col];
        if (relu) v = fmaxf(v, 0.0f);
        if (mode == 1) {
            ((unsigned short*)C)[(size_t)row * ldc + col] = f2bf(v);
        } else {    // KV: K natural (128 cols), V transposed [b,h,d,slot]
            if (col < 128) {
                ((unsigned short*)C)[(size_t)row * 128 + col] = f2bf(v);
            } else {
                int ch = col - 128, hh = ch >> 4, dd = ch & 15;
                int kg = row & 1023;                       // global key in batch
                int w  = kg & 127;                         // within 128-chunk
                // slot: w = 32t+16b+4qd+c -> slot = 32t+8qd+4b+c
                int slot = ((w >> 5) << 5) | (((w >> 2) & 3) << 3)
                         | (((w >> 4) & 1) << 2) | (w & 3);
                int kpos = (kg & ~127) | slot;
                ((unsigned short*)C2)[(((size_t)(row >> 10) * 8 + hh) * 16 + dd) * 1024
                                      + kpos] = f2bf(v);
            }
        }
    }
}

__global__ __launch_bounds__(256)
void gemm64_kernel(const unsigned short* __restrict__ A,
                   const unsigned short* __restrict__ Wt,
                   void* __restrict__ C, void* __restrict__ C2, int K,
                   const float* __restrict__ bias, const float* __restrict__ rowscale,
                   int relu, int mode)
{
    __shared__ unsigned short As[64 * 72];
    __shared__ unsigned short Ws[64 * 72];
    gemm64_body(As, Ws, A, Wt, C, C2, K, gridDim.y * 64, bias, rowscale, relu, mode,
                blockIdx.x, blockIdx.y);
}

// Q-proj (y<2) + KV-proj (y in 2..5) in one dispatch. Branch is block-uniform.
__global__ __launch_bounds__(256)
void qkv_kernel(const unsigned short* __restrict__ Yh, const unsigned short* __restrict__ wtq,
                unsigned short* __restrict__ Qh,
                const unsigned short* __restrict__ Bh, const unsigned short* __restrict__ wtkv,
                unsigned short* __restrict__ Kg, unsigned short* __restrict__ Vtg)
{
    __shared__ unsigned short As[64 * 72];
    __shared__ unsigned short Ws[64 * 72];
    if (blockIdx.y < 2)
        gemm64_body(As, Ws, Yh, wtq, Qh, nullptr, 128, 128, nullptr, nullptr, 0, 1,
                    blockIdx.x, blockIdx.y);
    else
        gemm64_body(As, Ws, Bh, wtkv, Kg, Vtg, 128, 256, nullptr, nullptr, 0, 2,
                    blockIdx.x, blockIdx.y - 2);
}

// ---------------------------------------------------------------------------
// gemm_ln: 32x128 tile, BK=64; per-wave 32x32 (one f32x16 acc), reg-prefetch
// K-loop (R21). Grid BM/32 = 1024 blocks; LDS 23.0 KB -> 4 blocks/CU.
// R22: residual is bf16 (resid_in == yh, in-place); f32 out only when fout
// non-null (final layer -> d_out). Epilogue = bias + resid + LayerNorm.
// LDS reused as f32 stash [32][130]. LN row = 8 threads x 16 cols.
// ---------------------------------------------------------------------------
__global__ __launch_bounds__(256)
void gemm_ln_kernel(const unsigned short* __restrict__ A,
                    const unsigned short* __restrict__ Wt, int K,
                    const float* __restrict__ bias,
                    const unsigned short* __restrict__ resid_in,
                    float* __restrict__ fout,
                    unsigned short* __restrict__ yh,
                    const float* __restrict__ lng, const float* __restrict__ lnb)
{
    __shared__ __align__(16) unsigned char smraw[23040];  // As[32][72] 4608 | Ws[128][72] 18432
    unsigned short* As = (unsigned short*)smraw;           // [32][72]
    unsigned short* Ws = (unsigned short*)(smraw + 4608);  // [128][72]

    const int tid  = threadIdx.x;
    const int lane = tid & 63, wave = tid >> 6;
    const int m31 = lane & 31, hi = lane >> 5;
    const int row0 = blockIdx.x * 32;
    const int wcol = wave * 32;                     // wave owns cols wcol..wcol+31
    const int sr = tid >> 3, sk = (tid & 7) * 8;    // A staging: 32 rows x 8 slots
    const int wr = tid >> 1, wo = (tid & 1) * 32;   // W staging: 128 rows x 2 halves

    const unsigned short* Ap = &A [(size_t)(row0 + sr) * K + sk];
    const unsigned short* Wp = &Wt[(size_t)wr * K + wo];

    short8 ra0 = *(const short8*)(Ap);
    short8 rw0 = *(const short8*)(Wp);
    short8 rw1 = *(const short8*)(Wp + 8);
    short8 rw2 = *(const short8*)(Wp + 16);
    short8 rw3 = *(const short8*)(Wp + 24);

    f32x16 acc = {};

    for (int kt = 0; kt < K; kt += 64) {
        *(short8*)&As[sr * 72 + sk]      = ra0;   // vmcnt wait hidden (issued one
        *(short8*)&Ws[wr * 72 + wo]      = rw0;   // compute-phase ago)
        *(short8*)&Ws[wr * 72 + wo + 8]  = rw1;
        *(short8*)&Ws[wr * 72 + wo + 16] = rw2;
        *(short8*)&Ws[wr * 72 + wo + 24] = rw3;
        if (kt + 64 < K) {                         // issue next chunk pre-barrier
            ra0 = *(const short8*)(Ap + kt + 64);
            rw0 = *(const short8*)(Wp + kt + 64);
            rw1 = *(const short8*)(Wp + kt + 72);
            rw2 = *(const short8*)(Wp + kt + 80);
            rw3 = *(const short8*)(Wp + kt + 88);
        }
        __syncthreads();
        #pragma unroll
        for (int ks = 0; ks < 4; ++ks) {
            short8 af = *(const short8*)&As[m31 * 72 + ks * 16 + hi * 8];
            short8 bf = *(const short8*)&Ws[(wcol + m31) * 72 + ks * 16 + hi * 8];
            acc = __builtin_amdgcn_mfma_f32_32x32x16_bf16(af, bf, acc, 0, 0, 0);
        }
        __syncthreads();   // readers done; also fences last iter before stash
    }

    // --- stash t into LDS, then per-row residual + LN ---
    float* Ts = (float*)smraw;    // [32][130]
    {
        const int col = wcol + m31;
        #pragma unroll
        for (int r = 0; r < 16; ++r) {
            const int rl = (r & 3) + 8 * (r >> 2) + 4 * hi;
            float v = acc[r];
            if (bias) v += bias[col];
            Ts[rl * 130 + col] = v;
        }
    }
    __syncthreads();
    const int r  = tid >> 3;       // 0..31
    const int cq = tid & 7;        // 8 threads per row, 16 cols each
    const int row = row0 + r;
    float v[16], s1 = 0.f, s2 = 0.f;
    const unsigned short* yr = resid_in + (size_t)row * 128 + cq * 16;
    #pragma unroll
    for (int i = 0; i < 4; ++i) {
        uint2 yv = *(const uint2*)&yr[i * 4];    // 4 bf16
        float ys[4] = {bflo(yv.x), bfhi(yv.x), bflo(yv.y), bfhi(yv.y)};
        #pragma unroll
        for (int j = 0; j < 4; ++j) {
            float t = Ts[r * 130 + cq * 16 + i * 4 + j] + ys[j];
            v[i * 4 + j] = t; s1 += t; s2 += t * t;
        }
    }
    s1 += __shfl_xor(s1, 1, 64); s1 += __shfl_xor(s1, 2, 64); s1 += __shfl_xor(s1, 4, 64);
    s2 += __shfl_xor(s2, 1, 64); s2 += __shfl_xor(s2, 2, 64); s2 += __shfl_xor(s2, 4, 64);
    const float mu  = s1 * (1.0f / 128.0f);
    const float inv = rsqrtf(s2 * (1.0f / 128.0f) - mu * mu + 1e-5f);
    unsigned short* yhr = yh + (size_t)row * 128 + cq * 16;
    #pragma unroll
    for (int i = 0; i < 4; ++i) {
        float o0 = (v[i*4+0] - mu) * inv * lng[cq*16 + i*4 + 0] + lnb[cq*16 + i*4 + 0];
        float o1 = (v[i*4+1] - mu) * inv * lng[cq*16 + i*4 + 1] + lnb[cq*16 + i*4 + 1];
        float o2 = (v[i*4+2] - mu) * inv * lng[cq*16 + i*4 + 2] + lnb[cq*16 + i*4 + 2];
        float o3 = (v[i*4+3] - mu) * inv * lng[cq*16 + i*4 + 3] + lnb[cq*16 + i*4 + 3];
        if (fout) {
            float4 ov; ov.x = o0; ov.y = o1; ov.z = o2; ov.w = o3;
            *(float4*)&fout[(size_t)row * 128 + cq * 16 + i * 4] = ov;
        }
        ushort4 hv; hv.x = f2bf(o0); hv.y = f2bf(o1); hv.z = f2bf(o2); hv.w = f2bf(o3);
        *(ushort4*)&yhr[i * 4] = hv;
    }
}

// ---------------------------------------------------------------------------
// GCN gather (bf16 in/out): one wave per node, 2 channels per lane.
// (R19 form: scalar neighbor indices, 4-deep load window.)
// ---------------------------------------------------------------------------
__global__ __launch_bounds__(256)
void gather_kernel(const unsigned short* __restrict__ hs, const int* __restrict__ csr_off,
                   const int* __restrict__ csr_src, const float* __restrict__ dinv,
                   const float* __restrict__ bias, unsigned short* __restrict__ out, int N)
{
    const int node = blockIdx.x * 4 + (threadIdx.x >> 6);
    const int lane = threadIdx.x & 63;
    const int s0 = __builtin_amdgcn_readfirstlane(csr_off[node]);
    const int s1 = __builtin_amdgcn_readfirstlane(csr_off[node + 1]);
    const unsigned* hsu = (const unsigned*)hs;

    unsigned u = hsu[(size_t)node * 64 + lane];
    float a0 = bflo(u), a1 = bfhi(u);

    int j = s0;
    for (; j + 4 <= s1; j += 4) {
        int i0 = csr_src[j];        // wave-uniform -> scalar pipe
        int i1 = csr_src[j + 1];
        int i2 = csr_src[j + 2];
        int i3 = csr_src[j + 3];
        unsigned uA = hsu[(size_t)i0 * 64 + lane];
        unsigned uB = hsu[(size_t)i1 * 64 + lane];
        unsigned uC = hsu[(size_t)i2 * 64 + lane];
        unsigned uD = hsu[(size_t)i3 * 64 + lane];
        a0 += (bflo(uA) + bflo(uB)) + (bflo(uC) + bflo(uD));
        a1 += (bfhi(uA) + bfhi(uB)) + (bfhi(uC) + bfhi(uD));
    }
    for (; j < s1; ++j) {
        int ib = csr_src[j];
        unsigned ub = hsu[(size_t)ib * 64 + lane];
        a0 += bflo(ub); a1 += bfhi(ub);
    }
    float di = dinv[node];
    float v0 = fmaxf(a0 * di + bias[lane * 2],     0.0f);
    float v1 = fmaxf(a1 * di + bias[lane * 2 + 1], 0.0f);
    ((unsigned*)out)[(size_t)node * 64 + lane] =
        ((unsigned)f2bf(v1) << 16) | (unsigned)f2bf(v0);
}

// ---------------------------------------------------------------------------
// MFMA flash cross-attention. Block = (64q, head, batch), wave owns 16 q,
// 128-key chunks. SWAPPED QK^T (no P LDS): lane (quad,l16) holds scores for
// q=l16, keys {16g+4quad+r}; exp+pack feed PV A-fragment; Vtg pre-permuted.
// l = P*ones via MFMA. R22: DOUBLE-BUFFERED Ks/Vt (17KB) -> 1 barrier/chunk:
// compute(it from buf[cur]) -> write buf[cur^1](it+1) -> barrier. Writers of
// buf[cur^1] are safe: its last readers finished before the it-1 barrier.
// ---------------------------------------------------------------------------
__global__ __launch_bounds__(256)
void attn_mfma_kernel(const unsigned short* __restrict__ Qh,
                      const unsigned short* __restrict__ Kg,
                      const unsigned short* __restrict__ Vtg,
                      unsigned short* __restrict__ Obh)
{
    __shared__ __align__(16) unsigned short Ks[2][128 * 16];  // [buf][key][dim]
    __shared__ __align__(16) unsigned short Vt[2][16 * 136];  // [buf][dim][slot]

    const int tid  = threadIdx.x;
    const int lane = tid & 63, wave = tid >> 6;
    const int quad = lane >> 4, l16 = lane & 15;
    const int q0 = blockIdx.x * 64, h = blockIdx.y, b = blockIdx.z;

    // staging coords (fixed per thread)
    const int key  = tid >> 1, half = (tid & 1) * 8;
    const int dim  = tid >> 4, kc = (tid & 15) * 8;
    const unsigned short* Kp = &Kg[((size_t)b * 1024 + key) * 128 + h * 16 + half];
    const unsigned short* Vp = &Vtg[(((size_t)b * 8 + h) * 16 + dim) * 1024 + kc];

    short8 qa = {};
    if (quad < 2) {
        qa = *(const short8*)&Qh[((size_t)b * 1024 + q0 + wave * 16 + l16) * 128 + h * 16 + quad * 8];
    }

    const short one_bf = (short)0x3F80;       // bf16 1.0
    const short8 onesv = {one_bf, one_bf, one_bf, one_bf,
                          one_bf, one_bf, one_bf, one_bf};

    f32x4 o    = {0.f, 0.f, 0.f, 0.f};
    f32x4 lacc = {0.f, 0.f, 0.f, 0.f};        // l via MFMA: P * ones
    const int kread = (quad & 1) * 8;   // quad>=2 lanes duplicate (qa==0 there)

    // prologue: chunk 0 -> buf0; issue chunk 1 loads
    short8 kreg = *(const short8*)(Kp);
    short8 vreg = *(const short8*)(Vp);
    *(short8*)&Ks[0][key * 16 + half] = kreg;
    *(short8*)&Vt[0][dim * 136 + kc]  = vreg;
    kreg = *(const short8*)(Kp + (size_t)128 * 128);
    vreg = *(const short8*)(Vp + 128);
    __syncthreads();

    for (int it = 0; it < 8; ++it) {
        const int cur = it & 1;

        f32x4 s[8];
        f32x4 zc = {0.f, 0.f, 0.f, 0.f};
        #pragma unroll
        for (int g = 0; g < 8; ++g) {
            short8 kb = *(const short8*)&Ks[cur][(g * 16 + l16) * 16 + kread];
            s[g] = __builtin_amdgcn_mfma_f32_16x16x32_bf16(kb, qa, zc, 0, 0, 0);  // swapped
        }

        #pragma unroll
        for (int t = 0; t < 4; ++t) {
            float p00 = fast_exp2(s[2*t][0]);
            float p01 = fast_exp2(s[2*t][1]);
            float p02 = fast_exp2(s[2*t][2]);
            float p03 = fast_exp2(s[2*t][3]);
            float p10 = fast_exp2(s[2*t+1][0]);
            float p11 = fast_exp2(s[2*t+1][1]);
            float p12 = fast_exp2(s[2*t+1][2]);
            float p13 = fast_exp2(s[2*t+1][3]);
            uint4 pk;
            pk.x = __builtin_amdgcn_perm(__builtin_bit_cast(unsigned, p01),
                                         __builtin_bit_cast(unsigned, p00), 0x07060302u);
            pk.y = __builtin_amdgcn_perm(__builtin_bit_cast(unsigned, p03),
                                         __builtin_bit_cast(unsigned, p02), 0x07060302u);
            pk.z = __builtin_amdgcn_perm(__builtin_bit_cast(unsigned, p11),
                                         __builtin_bit_cast(unsigned, p10), 0x07060302u);
            pk.w = __builtin_amdgcn_perm(__builtin_bit_cast(unsigned, p13),
                                         __builtin_bit_cast(unsigned, p12), 0x07060302u);
            short8 pa = __builtin_bit_cast(short8, pk);
            short8 vb = *(const short8*)&Vt[cur][l16 * 136 + t * 32 + quad * 8];
            o    = __builtin_amdgcn_mfma_f32_16x16x32_bf16(pa, vb, o, 0, 0, 0);
            lacc = __builtin_amdgcn_mfma_f32_16x16x32_bf16(pa, onesv, lacc, 0, 0, 0);
        }

        if (it < 7) {
            *(short8*)&Ks[cur ^ 1][key * 16 + half] = kreg;   // chunk it+1
            *(short8*)&Vt[cur ^ 1][dim * 136 + kc]  = vreg;
            if (it < 6) {                                      // issue chunk it+2
                kreg = *(const short8*)(Kp + (size_t)(it + 2) * 128 * 128);
                vreg = *(const short8*)(Vp + (it + 2) * 128);
            }
            __syncthreads();
        }
    }

    #pragma unroll
    for (int r = 0; r < 4; ++r) {
        float linv = 1.0f / lacc[r];           // replicated across cols l16
        int qrow = q0 + wave * 16 + quad * 4 + r;
        Obh[((size_t)b * 1024 + qrow) * 128 + h * 16 + l16] = f2bf(o[r] * linv);
    }
}

// ---------------------------------------------------------------------------
extern "C" void kernel_launch(void* const* d_in, const int* in_sizes, int n_in,
                              void* d_out, int out_size, void* d_ws, size_t ws_size,
                              hipStream_t stream)
{
    const float* enc  = (const float*)d_in[0];
    const float* xraw = (const float*)d_in[2];
    const int*   ei   = (const int*)d_in[3];
    const float* Wg1  = (const float*)d_in[4];
    const float* bg1  = (const float*)d_in[5];
    const float* Wg2  = (const float*)d_in[6];
    const float* bg2  = (const float*)d_in[7];
    const float* Wq   = (const float*)d_in[8];
    const float* Wk   = (const float*)d_in[9];
    const float* Wv   = (const float*)d_in[10];
    const float* Wo   = (const float*)d_in[11];
    const float* Wff1 = (const float*)d_in[12];
    const float* bff1 = (const float*)d_in[13];
    const float* Wff2 = (const float*)d_in[14];
    const float* bff2 = (const float*)d_in[15];
    const float* ln1g = (const float*)d_in[16];
    const float* ln1b = (const float*)d_in[17];
    const float* ln2g = (const float*)d_in[18];
    const float* ln2b = (const float*)d_in[19];

    const int E  = in_sizes[3] / 2;            // 524288
    const int N  = in_sizes[2] / 128;          // 32768
    const int BM = in_sizes[0] / 128;          // 32768
    const int B  = BM / 1024;                  // 32
    const int L  = in_sizes[8] / (128 * 128);  // 2

    const int* srcE = ei;
    const int* dstE = ei + E;

    const size_t ND = (size_t)N * 128;         // 4194304

    // --- workspace layout: atomics at the BOTTOM; bufYh 256B-ALIGNED ---
    float* ws   = (float*)d_ws;
    float* dinv = ws;                          // N f32
    int* cnt     = (int*)(ws + 32768);         // N
    int* csr_off = cnt + N;                    // N+1 (padded to N+4)
    int* cursor  = csr_off + N + 4;            // N
    int* csr_src = cursor + N;                 // E
    int* partial = csr_src + E;                // 128
    int* pbase   = partial + 128;              // 128 (layout keeper)
    unsigned short* bufYh =
        (unsigned short*)(((uintptr_t)(pbase + 128) + 255) & ~(uintptr_t)255);
    unsigned short* bufBh = bufYh + ND;        // ND bf16 (GCN features / KV src)
    unsigned short* region = bufBh + ND;       // 4*ND bf16
    unsigned short* Qh  = region;              // ND   (transformer phase)
    unsigned short* Kg  = region + ND;         // ND  [b*1024+key][128]
    unsigned short* Vtg = region + 2 * ND;     // ND  [b,h,d][1024 slots]
    unsigned short* Th  = region + 3 * ND;     // ND (attn out)
    unsigned short* Hh  = region;              // FFN hidden (4*ND), overlaps
    unsigned short* hsh   = region;            // GCN gemm out (dead before Qh)
    unsigned short* xrawh = region + ND;       // x_raw bf16  (dead before Kg)
    unsigned short* wt  = region + 4 * ND;     // 425984 bf16 (workspace tail)

    // --- CSR + dinv (hierarchical scan; scanB folded into scanC) ---
    hipMemsetAsync(cnt, 0, (size_t)N * sizeof(int), stream);
    count_kernel<<<(E + 255) / 256, 256, 0, stream>>>(dstE, cnt, E);
    scanA_kernel<<<N / 256, 256, 0, stream>>>(cnt, partial);
    scanC_kernel<<<N / 256, 256, 0, stream>>>(cnt, partial, csr_off, cursor, dinv, N, E);
    place_kernel<<<(E + 255) / 256, 256, 0, stream>>>(srcE, dstE, cursor, csr_src, E);

    // --- fused converts + weight transpose (1 dispatch) ---
    const int nconv = (int)(ND / 1024);        // 4096
    prep_kernel<<<2 * nconv + 14 * 256, 256, 0, stream>>>(
        xraw, xrawh, enc, bufYh,
        Wg1, Wg2, Wq, Wk, Wv, Wo, Wff1, Wff2, wt, nconv);

    // --- GCN layer 1 ---
    gemm64_kernel<<<dim3(N / 64, 2), 256, 0, stream>>>(xrawh, wt, hsh, nullptr, 128,
        nullptr, dinv, 0, 1);
    gather_kernel<<<N / 4, 256, 0, stream>>>(hsh, csr_off, csr_src, dinv, bg1, bufBh, N);
    // --- GCN layer 2 ---
    gemm64_kernel<<<dim3(N / 64, 2), 256, 0, stream>>>(bufBh, wt + 16384, hsh, nullptr, 128,
        nullptr, dinv, 0, 1);
    gather_kernel<<<N / 4, 256, 0, stream>>>(hsh, csr_off, csr_src, dinv, bg2, bufBh, N);
    // bufBh = GCN features (KV source)

    for (int l = 0; l < L; ++l) {
        const unsigned short* wtq  = wt + 32768  + (size_t)l * 16384;
        const unsigned short* wtkv = wt + 65536  + (size_t)l * 32768;
        const unsigned short* wto  = wt + 131072 + (size_t)l * 16384;
        const unsigned short* wtf1 = wt + 163840 + (size_t)l * 65536;
        const unsigned short* wtf2 = wt + 294912 + (size_t)l * 65536;

        // Q-proj + KV-proj fused (1 dispatch)
        qkv_kernel<<<dim3(BM / 64, 6), 256, 0, stream>>>(bufYh, wtq, Qh,
                                                         bufBh, wtkv, Kg, Vtg);

        attn_mfma_kernel<<<dim3(16, 8, B), 256, 0, stream>>>(Qh, Kg, Vtg, Th);

        // O-proj + residual + LN1 (fused), bf16 resid in-place
        gemm_ln_kernel<<<BM / 32, 256, 0, stream>>>(Th, wto, 128, nullptr,
            bufYh, nullptr, bufYh, ln1g + l * 128, ln1b + l * 128);

        gemm64_kernel<<<dim3(BM / 64, 8), 256, 0, stream>>>(bufYh, wtf1, Hh, nullptr, 128,
            bff1 + l * 512, nullptr, 1, 1);

        // FFN2 + residual + LN2 (fused); final layer also writes f32 d_out
        float* rout = (l == L - 1) ? (float*)d_out : nullptr;
        gemm_ln_kernel<<<BM / 32, 256, 0, stream>>>(Hh, wtf2, 512, bff2 + l * 128,
            bufYh, rout, bufYh, ln2g + l * 128, ln2b + l * 128);
    }
}

// Round 14
// 461.536 us; speedup vs baseline: 1.0562x; 1.0064x over previous
//
#include <hip/hip_runtime.h>
#include <math.h>

// GCN(2 layers, N=32768, E=524288, d=128) -> 2-layer cross-attention
// transformer (B=32, M=1024, d=128, H=8, dh=16, dff=512).
// R23: attn reverted to R21 single-buffer 2-barrier form — R22's double
//   buffer cost ~1.3us/dispatch (exp2-bound loop doesn't stall on barriers;
//   2x LDS write set + deeper prefetch chain hurt). Keeps R22's bf16
//   residual (-16.6us total: bufY f32 master dropped, bufYh sole residual,
//   LN recompute makes rounding non-compounding, absmax held 0.03125).
// Config ledger: swapped-QK attn (no P LDS, ~50.7us exp2 floor), gemm64
//   R17-form 8wg/CU, gemm_ln 32x128 + reg-prefetch 4wg/CU, scalar-idx
//   gather (transaction-bound; fp8 and shuffle variants both regressed),
//   prep/qkv fused, scanB folded, bufYh 256B-aligned, atomics at ws bottom.

typedef __attribute__((ext_vector_type(8)))  short short8;   // 8 bf16 = 4 VGPRs
typedef __attribute__((ext_vector_type(4)))  float f32x4;
typedef __attribute__((ext_vector_type(16))) float f32x16;

__device__ __forceinline__ unsigned short f2bf(float x) {   // RNE fp32->bf16
    unsigned u = __builtin_bit_cast(unsigned, x);
    u = (u + 0x7FFFu + ((u >> 16) & 1u)) >> 16;
    return (unsigned short)u;
}
__device__ __forceinline__ float bflo(unsigned u) { return __builtin_bit_cast(float, u << 16); }
__device__ __forceinline__ float bfhi(unsigned u) { return __builtin_bit_cast(float, u & 0xffff0000u); }
__device__ __forceinline__ float fast_exp2(float x) {       // D = 2^S0
    float r; asm("v_exp_f32 %0, %1" : "=v"(r) : "v"(x)); return r;
}

// ---------------------------------------------------------------------------
// CSR build
// ---------------------------------------------------------------------------
__global__ void count_kernel(const int* __restrict__ dst, int* __restrict__ cnt, int E) {
    int e = blockIdx.x * 256 + threadIdx.x;
    if (e < E) atomicAdd(&cnt[dst[e]], 1);
}

// partial[b] = sum of cnt[b*256 .. b*256+255]
__global__ __launch_bounds__(256)
void scanA_kernel(const int* __restrict__ cnt, int* __restrict__ partial)
{
    __shared__ int wsum[4];
    int t = threadIdx.x;
    int v = cnt[blockIdx.x * 256 + t];
    #pragma unroll
    for (int off = 32; off; off >>= 1) v += __shfl_xor(v, off, 64);
    if ((t & 63) == 0) wsum[t >> 6] = v;
    __syncthreads();
    if (t == 0) partial[blockIdx.x] = wsum[0] + wsum[1] + wsum[2] + wsum[3];
}

// scanB folded in — each block derives base = sum(partial[0..b-1]).
// off[i] = base + exclusive-scan-within-block; cursor = off; dinv = rsqrt
__global__ __launch_bounds__(256)
void scanC_kernel(const int* __restrict__ cnt, const int* __restrict__ partial,
                  int* __restrict__ off, int* __restrict__ cursor,
                  float* __restrict__ dinv, int N, int E)
{
    __shared__ int p[256];
    __shared__ int bsum[4];
    int t = threadIdx.x, b = blockIdx.x;
    int pv = (t < b) ? partial[t] : 0;      // b <= 127 < 128 entries
    #pragma unroll
    for (int o = 32; o; o >>= 1) pv += __shfl_xor(pv, o, 64);
    if ((t & 63) == 0) bsum[t >> 6] = pv;
    __syncthreads();
    const int base = bsum[0] + bsum[1] + bsum[2] + bsum[3];
    int i = b * 256 + t;
    int c = cnt[i];
    p[t] = c;
    __syncthreads();
    for (int o = 1; o < 256; o <<= 1) {
        int q = (t >= o) ? p[t - o] : 0;
        __syncthreads();
        p[t] += q;
        __syncthreads();
    }
    int ex = base + p[t] - c;
    off[i] = ex;
    cursor[i] = ex;
    dinv[i] = rsqrtf((float)c + 1.0f);
    if (b == 0 && t == 0) off[N] = E;
}

__global__ void place_kernel(const int* __restrict__ src, const int* __restrict__ dst,
                             int* __restrict__ cursor, int* __restrict__ csr_src, int E)
{
    int e = blockIdx.x * 256 + threadIdx.x;
    if (e < E) {
        int p = atomicAdd(&cursor[dst[e]], 1);
        csr_src[p] = src[e];
    }
}

// ---------------------------------------------------------------------------
// prep_kernel: fused conv(xraw->xrawh) | conv(enc->bufYh) | wtrans.
// Wq scale = 0.25 * log2(e): scores come out pre-multiplied for exp2.
// ---------------------------------------------------------------------------
__global__ __launch_bounds__(256)
void prep_kernel(const float* __restrict__ xraw, unsigned short* __restrict__ xrawh,
                 const float* __restrict__ enc, unsigned short* __restrict__ bufYh,
                 const float* Wg1, const float* Wg2, const float* Wq, const float* Wk,
                 const float* Wv, const float* Wo, const float* Wff1, const float* Wff2,
                 unsigned short* __restrict__ out, int nconv)
{
    const int bid = blockIdx.x, tid = threadIdx.x;
    if (bid < 2 * nconv) {                   // conv: xraw->xrawh | enc->bufYh
        const float* s = (bid < nconv) ? xraw : enc;
        unsigned short* d = (bid < nconv) ? xrawh : bufYh;
        int i = ((bid < nconv) ? bid : bid - nconv) * 256 + tid;
        float4 v = ((const float4*)s)[i];
        ushort4 h; h.x = f2bf(v.x); h.y = f2bf(v.y); h.z = f2bf(v.z); h.w = f2bf(v.w);
        ((ushort4*)d)[i] = h;
        return;
    }
    const int bid2 = bid - 2 * nconv;
    const int slot = bid2 >> 8;              // 14 slots x 256 blocks
    const int bx   = bid2 & 255;
    const float* src; int ks; int Ns; size_t doff; float scale = 1.0f;
    if      (slot == 0)  { src = Wg1;                        ks = 7; Ns = 128; doff = 0; }
    else if (slot == 1)  { src = Wg2;                        ks = 7; Ns = 128; doff = 16384; }
    else if (slot <= 3)  { src = Wq  + (slot - 2)  * 16384;  ks = 7; Ns = 128; doff = 32768  + (size_t)(slot - 2)  * 16384; scale = 0.36067376022f; }
    else if (slot <= 5)  { src = Wk  + (slot - 4)  * 16384;  ks = 7; Ns = 128; doff = 65536  + (size_t)(slot - 4)  * 32768; }
    else if (slot <= 7)  { src = Wv  + (slot - 6)  * 16384;  ks = 7; Ns = 128; doff = 65536  + (size_t)(slot - 6)  * 32768 + 16384; }
    else if (slot <= 9)  { src = Wo  + (slot - 8)  * 16384;  ks = 7; Ns = 128; doff = 131072 + (size_t)(slot - 8)  * 16384; }
    else if (slot <= 11) { src = Wff1 + (slot - 10) * 65536; ks = 7; Ns = 512; doff = 163840 + (size_t)(slot - 10) * 65536; }
    else                 { src = Wff2 + (slot - 12) * 65536; ks = 9; Ns = 128; doff = 294912 + (size_t)(slot - 12) * 65536; }
    const int total = Ns << ks;
    int id = bx * 256 + tid;
    if (id >= total) return;
    int n = id >> ks;
    int k = id & ((1 << ks) - 1);
    out[doff + id] = f2bf(src[(size_t)k * Ns + n] * scale);
}

// ---------------------------------------------------------------------------
// gemm64_body: 64x64 tile, BK=64, 18.4 KB LDS -> 8 wg/CU (R17 form).
// Wave = one 32x32 MFMA tile. mode 1: bf16 out (+bias/relu/rowscale), ldc.
// mode 2: KV split (col<128 -> K natural; col>=128 -> V transposed [b,h,d,slot]
//         with slot mapping: key w=32t+16b+4qd+c -> slot=32t+8qd+4b+c).
// C/D: col=lane&31, row=(reg&3)+8*(reg>>2)+4*(lane>>5)  [verified mapping].
// ---------------------------------------------------------------------------
__device__ __forceinline__
void gemm64_body(unsigned short* As, unsigned short* Ws,
                 const unsigned short* __restrict__ A,
                 const unsigned short* __restrict__ Wt,
                 void* __restrict__ C, void* __restrict__ C2, int K, int ldc,
                 const float* __restrict__ bias, const float* __restrict__ rowscale,
                 int relu, int mode, int bx, int by)
{
    const int tid  = threadIdx.x;
    const int lane = tid & 63, wave = tid >> 6;
    const int m31 = lane & 31, hi = lane >> 5;
    const int row0 = bx * 64;
    const int c0   = by * 64;
    const int wrow = (wave & 1) * 32;
    const int wcol = (wave >> 1) * 32;
    const int sr = tid >> 2, sk = (tid & 3) * 16;

    f32x16 acc = {};

    for (int kt = 0; kt < K; kt += 64) {
        if (kt) __syncthreads();
        *(short8*)&As[sr * 72 + sk]     = *(const short8*)&A [(size_t)(row0 + sr) * K + kt + sk];
        *(short8*)&As[sr * 72 + sk + 8] = *(const short8*)&A [(size_t)(row0 + sr) * K + kt + sk + 8];
        *(short8*)&Ws[sr * 72 + sk]     = *(const short8*)&Wt[(size_t)(c0   + sr) * K + kt + sk];
        *(short8*)&Ws[sr * 72 + sk + 8] = *(const short8*)&Wt[(size_t)(c0   + sr) * K + kt + sk + 8];
        __syncthreads();
        #pragma unroll
        for (int ks = 0; ks < 4; ++ks) {
            short8 af = *(const short8*)&As[(wrow + m31) * 72 + ks * 16 + hi * 8];
            short8 bf = *(const short8*)&Ws[(wcol + m31) * 72 + ks * 16 + hi * 8];
            acc = __builtin_amdgcn_mfma_f32_32x32x16_bf16(af, bf, acc, 0, 0, 0);
        }
    }

    const int col = c0 + wcol + m31;
    #pragma unroll
    for (int r = 0; r < 16; ++r) {
        const int row = row0 + wrow + (r & 3) + 8 * (r >> 2) + 4 * hi;
        float v = acc[r];
        if (rowscale) v *= rowscale[row];
        if (bias) v += bias[col];
        if (relu) v = fmaxf(v, 0.0f);
        if (mode == 1) {
            ((unsigned short*)C)[(size_t)row * ldc + col] = f2bf(v);
        } else {    // KV: K natural (128 cols), V transposed [b,h,d,slot]
            if (col < 128) {
                ((unsigned short*)C)[(size_t)row * 128 + col] = f2bf(v);
            } else {
                int ch = col - 128, hh = ch >> 4, dd = ch & 15;
                int kg = row & 1023;                       // global key in batch
                int w  = kg & 127;                         // within 128-chunk
                // slot: w = 32t+16b+4qd+c -> slot = 32t+8qd+4b+c
                int slot = ((w >> 5) << 5) | (((w >> 2) & 3) << 3)
                         | (((w >> 4) & 1) << 2) | (w & 3);
                int kpos = (kg & ~127) | slot;
                ((unsigned short*)C2)[(((size_t)(row >> 10) * 8 + hh) * 16 + dd) * 1024
                                      + kpos] = f2bf(v);
            }
        }
    }
}

__global__ __launch_bounds__(256)
void gemm64_kernel(const unsigned short* __restrict__ A,
                   const unsigned short* __restrict__ Wt,
                   void* __restrict__ C, void* __restrict__ C2, int K,
                   const float* __restrict__ bias, const float* __restrict__ rowscale,
                   int relu, int mode)
{
    __shared__ unsigned short As[64 * 72];
    __shared__ unsigned short Ws[64 * 72];
    gemm64_body(As, Ws, A, Wt, C, C2, K, gridDim.y * 64, bias, rowscale, relu, mode,
                blockIdx.x, blockIdx.y);
}

// Q-proj (y<2) + KV-proj (y in 2..5) in one dispatch. Branch is block-uniform.
__global__ __launch_bounds__(256)
void qkv_kernel(const unsigned short* __restrict__ Yh, const unsigned short* __restrict__ wtq,
                unsigned short* __restrict__ Qh,
                const unsigned short* __restrict__ Bh, const unsigned short* __restrict__ wtkv,
                unsigned short* __restrict__ Kg, unsigned short* __restrict__ Vtg)
{
    __shared__ unsigned short As[64 * 72];
    __shared__ unsigned short Ws[64 * 72];
    if (blockIdx.y < 2)
        gemm64_body(As, Ws, Yh, wtq, Qh, nullptr, 128, 128, nullptr, nullptr, 0, 1,
                    blockIdx.x, blockIdx.y);
    else
        gemm64_body(As, Ws, Bh, wtkv, Kg, Vtg, 128, 256, nullptr, nullptr, 0, 2,
                    blockIdx.x, blockIdx.y - 2);
}

// ---------------------------------------------------------------------------
// gemm_ln: 32x128 tile, BK=64; per-wave 32x32 (one f32x16 acc), reg-prefetch
// K-loop. Grid BM/32 = 1024 blocks; LDS 23.0 KB -> 4 blocks/CU.
// Residual is bf16 (resid_in == yh, in-place); f32 out only when fout
// non-null (final layer -> d_out). Epilogue = bias + resid + LayerNorm.
// LDS reused as f32 stash [32][130]. LN row = 8 threads x 16 cols.
// ---------------------------------------------------------------------------
__global__ __launch_bounds__(256)
void gemm_ln_kernel(const unsigned short* __restrict__ A,
                    const unsigned short* __restrict__ Wt, int K,
                    const float* __restrict__ bias,
                    const unsigned short* __restrict__ resid_in,
                    float* __restrict__ fout,
                    unsigned short* __restrict__ yh,
                    const float* __restrict__ lng, const float* __restrict__ lnb)
{
    __shared__ __align__(16) unsigned char smraw[23040];  // As[32][72] 4608 | Ws[128][72] 18432
    unsigned short* As = (unsigned short*)smraw;           // [32][72]
    unsigned short* Ws = (unsigned short*)(smraw + 4608);  // [128][72]

    const int tid  = threadIdx.x;
    const int lane = tid & 63, wave = tid >> 6;
    const int m31 = lane & 31, hi = lane >> 5;
    const int row0 = blockIdx.x * 32;
    const int wcol = wave * 32;                     // wave owns cols wcol..wcol+31
    const int sr = tid >> 3, sk = (tid & 7) * 8;    // A staging: 32 rows x 8 slots
    const int wr = tid >> 1, wo = (tid & 1) * 32;   // W staging: 128 rows x 2 halves

    const unsigned short* Ap = &A [(size_t)(row0 + sr) * K + sk];
    const unsigned short* Wp = &Wt[(size_t)wr * K + wo];

    short8 ra0 = *(const short8*)(Ap);
    short8 rw0 = *(const short8*)(Wp);
    short8 rw1 = *(const short8*)(Wp + 8);
    short8 rw2 = *(const short8*)(Wp + 16);
    short8 rw3 = *(const short8*)(Wp + 24);

    f32x16 acc = {};

    for (int kt = 0; kt < K; kt += 64) {
        *(short8*)&As[sr * 72 + sk]      = ra0;   // vmcnt wait hidden (issued one
        *(short8*)&Ws[wr * 72 + wo]      = rw0;   // compute-phase ago)
        *(short8*)&Ws[wr * 72 + wo + 8]  = rw1;
        *(short8*)&Ws[wr * 72 + wo + 16] = rw2;
        *(short8*)&Ws[wr * 72 + wo + 24] = rw3;
        if (kt + 64 < K) {                         // issue next chunk pre-barrier
            ra0 = *(const short8*)(Ap + kt + 64);
            rw0 = *(const short8*)(Wp + kt + 64);
            rw1 = *(const short8*)(Wp + kt + 72);
            rw2 = *(const short8*)(Wp + kt + 80);
            rw3 = *(const short8*)(Wp + kt + 88);
        }
        __syncthreads();
        #pragma unroll
        for (int ks = 0; ks < 4; ++ks) {
            short8 af = *(const short8*)&As[m31 * 72 + ks * 16 + hi * 8];
            short8 bf = *(const short8*)&Ws[(wcol + m31) * 72 + ks * 16 + hi * 8];
            acc = __builtin_amdgcn_mfma_f32_32x32x16_bf16(af, bf, acc, 0, 0, 0);
        }
        __syncthreads();   // readers done; also fences last iter before stash
    }

    // --- stash t into LDS, then per-row residual + LN ---
    float* Ts = (float*)smraw;    // [32][130]
    {
        const int col = wcol + m31;
        #pragma unroll
        for (int r = 0; r < 16; ++r) {
            const int rl = (r & 3) + 8 * (r >> 2) + 4 * hi;
            float v = acc[r];
            if (bias) v += bias[col];
            Ts[rl * 130 + col] = v;
        }
    }
    __syncthreads();
    const int r  = tid >> 3;       // 0..31
    const int cq = tid & 7;        // 8 threads per row, 16 cols each
    const int row = row0 + r;
    float v[16], s1 = 0.f, s2 = 0.f;
    const unsigned short* yr = resid_in + (size_t)row * 128 + cq * 16;
    #pragma unroll
    for (int i = 0; i < 4; ++i) {
        uint2 yv = *(const uint2*)&yr[i * 4];    // 4 bf16
        float ys[4] = {bflo(yv.x), bfhi(yv.x), bflo(yv.y), bfhi(yv.y)};
        #pragma unroll
        for (int j = 0; j < 4; ++j) {
            float t = Ts[r * 130 + cq * 16 + i * 4 + j] + ys[j];
            v[i * 4 + j] = t; s1 += t; s2 += t * t;
        }
    }
    s1 += __shfl_xor(s1, 1, 64); s1 += __shfl_xor(s1, 2, 64); s1 += __shfl_xor(s1, 4, 64);
    s2 += __shfl_xor(s2, 1, 64); s2 += __shfl_xor(s2, 2, 64); s2 += __shfl_xor(s2, 4, 64);
    const float mu  = s1 * (1.0f / 128.0f);
    const float inv = rsqrtf(s2 * (1.0f / 128.0f) - mu * mu + 1e-5f);
    unsigned short* yhr = yh + (size_t)row * 128 + cq * 16;
    #pragma unroll
    for (int i = 0; i < 4; ++i) {
        float o0 = (v[i*4+0] - mu) * inv * lng[cq*16 + i*4 + 0] + lnb[cq*16 + i*4 + 0];
        float o1 = (v[i*4+1] - mu) * inv * lng[cq*16 + i*4 + 1] + lnb[cq*16 + i*4 + 1];
        float o2 = (v[i*4+2] - mu) * inv * lng[cq*16 + i*4 + 2] + lnb[cq*16 + i*4 + 2];
        float o3 = (v[i*4+3] - mu) * inv * lng[cq*16 + i*4 + 3] + lnb[cq*16 + i*4 + 3];
        if (fout) {
            float4 ov; ov.x = o0; ov.y = o1; ov.z = o2; ov.w = o3;
            *(float4*)&fout[(size_t)row * 128 + cq * 16 + i * 4] = ov;
        }
        ushort4 hv; hv.x = f2bf(o0); hv.y = f2bf(o1); hv.z = f2bf(o2); hv.w = f2bf(o3);
        *(ushort4*)&yhr[i * 4] = hv;
    }
}

// ---------------------------------------------------------------------------
// GCN gather (bf16 in/out): one wave per node, 2 channels per lane.
// (R19 form: scalar neighbor indices, 4-deep load window.)
// ---------------------------------------------------------------------------
__global__ __launch_bounds__(256)
void gather_kernel(const unsigned short* __restrict__ hs, const int* __restrict__ csr_off,
                   const int* __restrict__ csr_src, const float* __restrict__ dinv,
                   const float* __restrict__ bias, unsigned short* __restrict__ out, int N)
{
    const int node = blockIdx.x * 4 + (threadIdx.x >> 6);
    const int lane = threadIdx.x & 63;
    const int s0 = __builtin_amdgcn_readfirstlane(csr_off[node]);
    const int s1 = __builtin_amdgcn_readfirstlane(csr_off[node + 1]);
    const unsigned* hsu = (const unsigned*)hs;

    unsigned u = hsu[(size_t)node * 64 + lane];
    float a0 = bflo(u), a1 = bfhi(u);

    int j = s0;
    for (; j + 4 <= s1; j += 4) {
        int i0 = csr_src[j];        // wave-uniform -> scalar pipe
        int i1 = csr_src[j + 1];
        int i2 = csr_src[j + 2];
        int i3 = csr_src[j + 3];
        unsigned uA = hsu[(size_t)i0 * 64 + lane];
        unsigned uB = hsu[(size_t)i1 * 64 + lane];
        unsigned uC = hsu[(size_t)i2 * 64 + lane];
        unsigned uD = hsu[(size_t)i3 * 64 + lane];
        a0 += (bflo(uA) + bflo(uB)) + (bflo(uC) + bflo(uD));
        a1 += (bfhi(uA) + bfhi(uB)) + (bfhi(uC) + bfhi(uD));
    }
    for (; j < s1; ++j) {
        int ib = csr_src[j];
        unsigned ub = hsu[(size_t)ib * 64 + lane];
        a0 += bflo(ub); a1 += bfhi(ub);
    }
    float di = dinv[node];
    float v0 = fmaxf(a0 * di + bias[lane * 2],     0.0f);
    float v1 = fmaxf(a1 * di + bias[lane * 2 + 1], 0.0f);
    ((unsigned*)out)[(size_t)node * 64 + lane] =
        ((unsigned)f2bf(v1) << 16) | (unsigned)f2bf(v0);
}

// ---------------------------------------------------------------------------
// MFMA flash cross-attention (R21 single-buffer form — R22's double buffer
// regressed ~1.3us/dispatch). Block = (64q, head, batch), wave owns 16 q,
// 128-key chunks. Ks natural [128 keys][16 dims] (4KB), byte-linear staging.
// SWAPPED QK^T: s[g] = mfma(kb, qa) -> lane (quad,l16) holds scores for
// q=l16, keys {16g+4quad+r}. exp + pack feed PV's A-fragment directly
// (P[q=l16][slot quad*8+j], slot->key = 32t+16(j>>2)+4quad+(j&3)); Vtg is
// pre-permuted to this slot order by the KV GEMM. No P LDS. quad>=2 lanes:
// qa=0 (B zero) x kb-garbage (finite) = 0 for k=16..31. l = P*ones via MFMA.
// ---------------------------------------------------------------------------
__global__ __launch_bounds__(256)
void attn_mfma_kernel(const unsigned short* __restrict__ Qh,
                      const unsigned short* __restrict__ Kg,
                      const unsigned short* __restrict__ Vtg,
                      unsigned short* __restrict__ Obh)
{
    __shared__ __align__(16) unsigned short Ks[128 * 16];  // [key][dim 0..15]
    __shared__ __align__(16) unsigned short Vt[16 * 136];  // [dim][slot 0..127]

    const int tid  = threadIdx.x;
    const int lane = tid & 63, wave = tid >> 6;
    const int quad = lane >> 4, l16 = lane & 15;
    const int q0 = blockIdx.x * 64, h = blockIdx.y, b = blockIdx.z;

    // staging coords (fixed per thread)
    const int key  = tid >> 1, half = (tid & 1) * 8;
    const int dim  = tid >> 4, kc = (tid & 15) * 8;
    const unsigned short* Kp = &Kg[((size_t)b * 1024 + key) * 128 + h * 16 + half];
    const unsigned short* Vp = &Vtg[(((size_t)b * 8 + h) * 16 + dim) * 1024 + kc];

    short8 qa = {};
    if (quad < 2) {
        qa = *(const short8*)&Qh[((size_t)b * 1024 + q0 + wave * 16 + l16) * 128 + h * 16 + quad * 8];
    }

    const short one_bf = (short)0x3F80;       // bf16 1.0
    const short8 onesv = {one_bf, one_bf, one_bf, one_bf,
                          one_bf, one_bf, one_bf, one_bf};

    f32x4 o    = {0.f, 0.f, 0.f, 0.f};
    f32x4 lacc = {0.f, 0.f, 0.f, 0.f};        // l via MFMA: P * ones
    const int kread = (quad & 1) * 8;   // quad>=2 lanes duplicate (qa==0 there)

    short8 kreg = *(const short8*)(Kp);        // chunk 0
    short8 vreg = *(const short8*)(Vp);

    for (int it = 0; it < 8; ++it) {
        *(short8*)&Ks[key * 16 + half] = kreg;  // byte-linear: addr = tid*16B
        *(short8*)&Vt[dim * 136 + kc]  = vreg;
        if (it < 7) {                            // issue chunk it+1 pre-barrier
            kreg = *(const short8*)(Kp + (size_t)(it + 1) * 128 * 128);
            vreg = *(const short8*)(Vp + (it + 1) * 128);
        }
        __syncthreads();

        f32x4 s[8];
        f32x4 zc = {0.f, 0.f, 0.f, 0.f};
        #pragma unroll
        for (int g = 0; g < 8; ++g) {
            short8 kb = *(const short8*)&Ks[(g * 16 + l16) * 16 + kread];
            s[g] = __builtin_amdgcn_mfma_f32_16x16x32_bf16(kb, qa, zc, 0, 0, 0);  // swapped
        }

        #pragma unroll
        for (int t = 0; t < 4; ++t) {
            float p00 = fast_exp2(s[2*t][0]);
            float p01 = fast_exp2(s[2*t][1]);
            float p02 = fast_exp2(s[2*t][2]);
            float p03 = fast_exp2(s[2*t][3]);
            float p10 = fast_exp2(s[2*t+1][0]);
            float p11 = fast_exp2(s[2*t+1][1]);
            float p12 = fast_exp2(s[2*t+1][2]);
            float p13 = fast_exp2(s[2*t+1][3]);
            uint4 pk;
            pk.x = __builtin_amdgcn_perm(__builtin_bit_cast(unsigned, p01),
                                         __builtin_bit_cast(unsigned, p00), 0x07060302u);
            pk.y = __builtin_amdgcn_perm(__builtin_bit_cast(unsigned, p03),
                                         __builtin_bit_cast(unsigned, p02), 0x07060302u);
            pk.z = __builtin_amdgcn_perm(__builtin_bit_cast(unsigned, p11),
                                         __builtin_bit_cast(unsigned, p10), 0x07060302u);
            pk.w = __builtin_amdgcn_perm(__builtin_bit_cast(unsigned, p13),
                                         __builtin_bit_cast(unsigned, p12), 0x07060302u);
            short8 pa = __builtin_bit_cast(short8, pk);
            short8 vb = *(const short8*)&Vt[l16 * 136 + t * 32 + quad * 8];
            o    = __builtin_amdgcn_mfma_f32_16x16x32_bf16(pa, vb, o, 0, 0, 0);
            lacc = __builtin_amdgcn_mfma_f32_16x16x32_bf16(pa, onesv, lacc, 0, 0, 0);
        }
        if (it < 7) __syncthreads();   // all waves done reading Ks/Vt chunk it
    }

    #pragma unroll
    for (int r = 0; r < 4; ++r) {
        float linv = 1.0f / lacc[r];           // replicated across cols l16
        int qrow = q0 + wave * 16 + quad * 4 + r;
        Obh[((size_t)b * 1024 + qrow) * 128 + h * 16 + l16] = f2bf(o[r] * linv);
    }
}

// ---------------------------------------------------------------------------
extern "C" void kernel_launch(void* const* d_in, const int* in_sizes, int n_in,
                              void* d_out, int out_size, void* d_ws, size_t ws_size,
                              hipStream_t stream)
{
    const float* enc  = (const float*)d_in[0];
    const float* xraw = (const float*)d_in[2];
    const int*   ei   = (const int*)d_in[3];
    const float* Wg1  = (const float*)d_in[4];
    const float* bg1  = (const float*)d_in[5];
    const float* Wg2  = (const float*)d_in[6];
    const float* bg2  = (const float*)d_in[7];
    const float* Wq   = (const float*)d_in[8];
    const float* Wk   = (const float*)d_in[9];
    const float* Wv   = (const float*)d_in[10];
    const float* Wo   = (const float*)d_in[11];
    const float* Wff1 = (const float*)d_in[12];
    const float* bff1 = (const float*)d_in[13];
    const float* Wff2 = (const float*)d_in[14];
    const float* bff2 = (const float*)d_in[15];
    const float* ln1g = (const float*)d_in[16];
    const float* ln1b = (const float*)d_in[17];
    const float* ln2g = (const float*)d_in[18];
    const float* ln2b = (const float*)d_in[19];

    const int E  = in_sizes[3] / 2;            // 524288
    const int N  = in_sizes[2] / 128;          // 32768
    const int BM = in_sizes[0] / 128;          // 32768
    const int B  = BM / 1024;                  // 32
    const int L  = in_sizes[8] / (128 * 128);  // 2

    const int* srcE = ei;
    const int* dstE = ei + E;

    const size_t ND = (size_t)N * 128;         // 4194304

    // --- workspace layout: atomics at the BOTTOM; bufYh 256B-ALIGNED ---
    float* ws   = (float*)d_ws;
    float* dinv = ws;                          // N f32
    int* cnt     = (int*)(ws + 32768);         // N
    int* csr_off = cnt + N;                    // N+1 (padded to N+4)
    int* cursor  = csr_off + N + 4;            // N
    int* csr_src = cursor + N;                 // E
    int* partial = csr_src + E;                // 128
    int* pbase   = partial + 128;              // 128 (layout keeper)
    unsigned short* bufYh =
        (unsigned short*)(((uintptr_t)(pbase + 128) + 255) & ~(uintptr_t)255);
    unsigned short* bufBh = bufYh + ND;        // ND bf16 (GCN features / KV src)
    unsigned short* region = bufBh + ND;       // 4*ND bf16
    unsigned short* Qh  = region;              // ND   (transformer phase)
    unsigned short* Kg  = region + ND;         // ND  [b*1024+key][128]
    unsigned short* Vtg = region + 2 * ND;     // ND  [b,h,d][1024 slots]
    unsigned short* Th  = region + 3 * ND;     // ND (attn out)
    unsigned short* Hh  = region;              // FFN hidden (4*ND), overlaps
    unsigned short* hsh   = region;            // GCN gemm out (dead before Qh)
    unsigned short* xrawh = region + ND;       // x_raw bf16  (dead before Kg)
    unsigned short* wt  = region + 4 * ND;     // 425984 bf16 (workspace tail)

    // --- CSR + dinv (hierarchical scan; scanB folded into scanC) ---
    hipMemsetAsync(cnt, 0, (size_t)N * sizeof(int), stream);
    count_kernel<<<(E + 255) / 256, 256, 0, stream>>>(dstE, cnt, E);
    scanA_kernel<<<N / 256, 256, 0, stream>>>(cnt, partial);
    scanC_kernel<<<N / 256, 256, 0, stream>>>(cnt, partial, csr_off, cursor, dinv, N, E);
    place_kernel<<<(E + 255) / 256, 256, 0, stream>>>(srcE, dstE, cursor, csr_src, E);

    // --- fused converts + weight transpose (1 dispatch) ---
    const int nconv = (int)(ND / 1024);        // 4096
    prep_kernel<<<2 * nconv + 14 * 256, 256, 0, stream>>>(
        xraw, xrawh, enc, bufYh,
        Wg1, Wg2, Wq, Wk, Wv, Wo, Wff1, Wff2, wt, nconv);

    // --- GCN layer 1 ---
    gemm64_kernel<<<dim3(N / 64, 2), 256, 0, stream>>>(xrawh, wt, hsh, nullptr, 128,
        nullptr, dinv, 0, 1);
    gather_kernel<<<N / 4, 256, 0, stream>>>(hsh, csr_off, csr_src, dinv, bg1, bufBh, N);
    // --- GCN layer 2 ---
    gemm64_kernel<<<dim3(N / 64, 2), 256, 0, stream>>>(bufBh, wt + 16384, hsh, nullptr, 128,
        nullptr, dinv, 0, 1);
    gather_kernel<<<N / 4, 256, 0, stream>>>(hsh, csr_off, csr_src, dinv, bg2, bufBh, N);
    // bufBh = GCN features (KV source)

    for (int l = 0; l < L; ++l) {
        const unsigned short* wtq  = wt + 32768  + (size_t)l * 16384;
        const unsigned short* wtkv = wt + 65536  + (size_t)l * 32768;
        const unsigned short* wto  = wt + 131072 + (size_t)l * 16384;
        const unsigned short* wtf1 = wt + 163840 + (size_t)l * 65536;
        const unsigned short* wtf2 = wt + 294912 + (size_t)l * 65536;

        // Q-proj + KV-proj fused (1 dispatch)
        qkv_kernel<<<dim3(BM / 64, 6), 256, 0, stream>>>(bufYh, wtq, Qh,
                                                         bufBh, wtkv, Kg, Vtg);

        attn_mfma_kernel<<<dim3(16, 8, B), 256, 0, stream>>>(Qh, Kg, Vtg, Th);

        // O-proj + residual + LN1 (fused), bf16 resid in-place
        gemm_ln_kernel<<<BM / 32, 256, 0, stream>>>(Th, wto, 128, nullptr,
            bufYh, nullptr, bufYh, ln1g + l * 128, ln1b + l * 128);

        gemm64_kernel<<<dim3(BM / 64, 8), 256, 0, stream>>>(bufYh, wtf1, Hh, nullptr, 128,
            bff1 + l * 512, nullptr, 1, 1);

        // FFN2 + residual + LN2 (fused); final layer also writes f32 d_out
        float* rout = (l == L - 1) ? (float*)d_out : nullptr;
        gemm_ln_kernel<<<BM / 32, 256, 0, stream>>>(Hh, wtf2, 512, bff2 + l * 128,
            bufYh, rout, bufYh, ln2g + l * 128, ln2b + l * 128);
    }
}